// Round 4
// baseline (232.535 us; speedup 1.0000x reference)
//
#include <hip/hip_runtime.h>

// ---- problem constants ----
#define NB 8192      // batch rows
#define NM 1024      // image dim
#define NK 2048      // dictionary size

typedef unsigned short ushort_t;
using bf16x8 = __attribute__((ext_vector_type(8))) short;
using f32x4  = __attribute__((ext_vector_type(4))) float;

struct Ctrl { double a; double b; int T; float alpha; };

__device__ __forceinline__ ushort_t f2bf(float f) {
  union { float f; unsigned u; } v; v.f = f;
  unsigned r = (v.u + 0x7FFFu + ((v.u >> 16) & 1u)) >> 16;  // RNE
  return (ushort_t)r;
}

__device__ __forceinline__ void gload_lds16(const void* g, void* l) {
  __builtin_amdgcn_global_load_lds(
      (const __attribute__((address_space(1))) unsigned int*)g,
      (__attribute__((address_space(3))) unsigned int*)l, 16, 0, 0);
}

// C = Aop(row-major [rows][KK]) * Bop^T (Bop row-major [cols][KK]); 128x128 tile,
// BK=64, 4 waves, each wave 64x64 via 4x4 frags of mfma_f32_16x16x32_bf16.
// MODE 0: sample-G0: write bf16 C, accumulate f64 sum(C^2) -> ctrl->a
// MODE 1: sample-P : no writes,    accumulate f64 sum(C^2) -> ctrl->b
// MODE 2: Q pass   : write bf16 C
// MODE 3: final    : write f32 (ctrl->alpha * C)
template<int MODE>
__global__ __launch_bounds__(256)
void gemm_bt(const ushort_t* __restrict__ Aop, const ushort_t* __restrict__ Bop,
             int KK, int njb, int outld,
             float* __restrict__ outf, ushort_t* __restrict__ outbf,
             Ctrl* __restrict__ ctrl)
{
  const int tid = threadIdx.x;
  const int w = tid >> 6, l = tid & 63;
  const int wm = w >> 1, wn = w & 1;
  const int bi = blockIdx.x / njb, bj = blockIdx.x % njb;
  const int i0 = bi * 128, j0 = bj * 128;
  const int l15 = l & 15, l16 = l >> 4;
  const int lr = l >> 3;          // staging row-within-8
  const int lc = (l & 7) * 8;     // staging col (elements)

  float al = 1.0f;
  if constexpr (MODE == 3) al = ctrl->alpha;

  __shared__ __align__(128) ushort_t As[128 * 64];
  __shared__ __align__(128) ushort_t Bs[128 * 64];
  __shared__ double red[4];

  f32x4 acc[4][4];
#pragma unroll
  for (int m = 0; m < 4; ++m)
#pragma unroll
    for (int n = 0; n < 4; ++n)
      acc[m][n] = (f32x4){0.f, 0.f, 0.f, 0.f};

  for (int k0 = 0; k0 < KK; k0 += 64) {
#pragma unroll
    for (int c = 0; c < 4; ++c) {
      const int rr = c * 32 + w * 8 + lr;
      const ushort_t* ga = Aop + ((size_t)(i0 + rr) * (size_t)KK + k0 + lc);
      const ushort_t* gb = Bop + ((size_t)(j0 + rr) * (size_t)KK + k0 + lc);
      const int base = w * 512 + c * 2048;  // wave-uniform LDS element base
      gload_lds16(ga, &As[base]);
      gload_lds16(gb, &Bs[base]);
    }
    __syncthreads();
#pragma unroll
    for (int ks = 0; ks < 2; ++ks) {
      bf16x8 af[4], bfr[4];
#pragma unroll
      for (int m = 0; m < 4; ++m)
        af[m] = *(const bf16x8*)&As[(wm * 64 + m * 16 + l15) * 64 + ks * 32 + l16 * 8];
#pragma unroll
      for (int n = 0; n < 4; ++n)
        bfr[n] = *(const bf16x8*)&Bs[(wn * 64 + n * 16 + l15) * 64 + ks * 32 + l16 * 8];
#pragma unroll
      for (int m = 0; m < 4; ++m)
#pragma unroll
        for (int n = 0; n < 4; ++n)
          acc[m][n] = __builtin_amdgcn_mfma_f32_16x16x32_bf16(af[m], bfr[n], acc[m][n], 0, 0, 0);
    }
    __syncthreads();
  }

  // epilogue: C/D layout col = lane&15, row = (lane>>4)*4 + reg
  double sq = 0.0;
#pragma unroll
  for (int m = 0; m < 4; ++m) {
#pragma unroll
    for (int n = 0; n < 4; ++n) {
      const int gr0 = i0 + wm * 64 + m * 16 + l16 * 4;
      const int gc  = j0 + wn * 64 + n * 16 + l15;
#pragma unroll
      for (int q4 = 0; q4 < 4; ++q4) {
        const size_t idx = (size_t)(gr0 + q4) * (size_t)outld + gc;
        const float v = acc[m][n][q4];
        if constexpr (MODE == 0 || MODE == 2) outbf[idx] = f2bf(v);
        if constexpr (MODE == 3)              outf[idx] = al * v;
        if constexpr (MODE == 0 || MODE == 1) sq += (double)v * (double)v;
      }
    }
  }
  if constexpr (MODE == 0 || MODE == 1) {
#pragma unroll
    for (int off = 32; off > 0; off >>= 1) sq += __shfl_down(sq, off, 64);
    if (l == 0) red[w] = sq;
    __syncthreads();
    if (tid == 0) {
      const double tot = red[0] + red[1] + red[2] + red[3];
      if constexpr (MODE == 0) atomicAdd(&ctrl->a, tot);
      else                     atomicAdd(&ctrl->b, tot);
    }
  }
}

__global__ void conv_img_k(const float* __restrict__ src, ushort_t* __restrict__ dst) {
  int i = blockIdx.x * blockDim.x + threadIdx.x;
  const int stride = gridDim.x * blockDim.x;
  const int n4 = (NB * NM) / 4;
  for (; i < n4; i += stride) {
    const float4 v = ((const float4*)src)[i];
    ushort4 o;
    o.x = f2bf(v.x); o.y = f2bf(v.y); o.z = f2bf(v.z); o.w = f2bf(v.w);
    ((ushort4*)dst)[i] = o;
  }
}

__global__ void conv_w_k(const float* __restrict__ W, ushort_t* __restrict__ Wbf,
                         ushort_t* __restrict__ Wt) {
  int i = blockIdx.x * blockDim.x + threadIdx.x;
  const int stride = gridDim.x * blockDim.x;
  for (; i < NM * NK; i += stride) {
    const ushort_t v = f2bf(W[i]);
    Wbf[i] = v;
    const int m = i >> 11, k = i & (NK - 1);
    Wt[k * NM + m] = v;
  }
}

// Scalar recurrence in the Krylov basis {G0, G0*A}:
//   r_t = alpha_t*G0 + beta_t*G0A, alpha_t = t*s, beta_t = -s^2 t(t-1)/2
//   ratio_t^2 = s^2(a - 2*ap*b) / (ap^2 a + 2 ap bp b),  ap/bp at t-1.
// Homogeneous in (a,b) -> sampled norms (any common scale) are valid inputs.
__global__ void solve_k(Ctrl* c) {
  const double s = 0.1 * (2.0 / 8388608.0);
  const double a = c->a, b = c->b;
  int T = 10000;
  for (int t = 1; t <= 10000; ++t) {
    const double ap = (double)(t - 1) * s;
    const double bp = -s * s * (double)(t - 1) * (double)(t - 2) * 0.5;
    const double num = s * s * (a - 2.0 * ap * b);
    const double den = ap * ap * a + 2.0 * ap * bp * b;
    if (den > 0.0 && num < 1e-4 * den) { T = t; break; }
  }
  c->T = T;
  c->alpha = (float)((double)T * s);
}

extern "C" void kernel_launch(void* const* d_in, const int* in_sizes, int n_in,
                              void* d_out, int out_size, void* d_ws, size_t ws_size,
                              hipStream_t stream) {
  (void)in_sizes; (void)n_in; (void)out_size; (void)ws_size;
  const float* img = (const float*)d_in[0];   // [8192][1024] f32
  const float* W   = (const float*)d_in[1];   // [1024][2048] f32, cols unit-norm

  float* Rr = (float*)d_out;                   // r = alpha*G0, f32 [8192][2048]
  float* Pp = Rr + (size_t)NB * NK;            // pred = alpha*img*Q, f32 [8192][1024]

  char* ws = (char*)d_ws;
  ushort_t* imgbf = (ushort_t*)(ws + 0);          // 16,777,216 B [8192][1024]
  ushort_t* Wt    = (ushort_t*)(ws + 16777216);   //  4,194,304 B [2048][1024]
  ushort_t* Wbf   = (ushort_t*)(ws + 20971520);   //  4,194,304 B [1024][2048]
  ushort_t* Qbf   = (ushort_t*)(ws + 25165824);   //  2,097,152 B [1024][1024]
  ushort_t* G0sbf = (ushort_t*)(ws + 27262976);   //  4,194,304 B [1024][2048] sample
  Ctrl*     ctrl  = (Ctrl*)(ws + 31457280);

  (void)hipMemsetAsync(ctrl, 0, sizeof(Ctrl), stream);

  conv_img_k<<<2048, 256, 0, stream>>>(img, imgbf);
  conv_w_k<<<2048, 256, 0, stream>>>(W, Wbf, Wt);

  // Q = W @ W^T : [1024x1024], KK=2048. A = Wbf rows, B^T = Wbf rows (symmetric).
  gemm_bt<2><<<64, 256, 0, stream>>>(Wbf, Wbf, NK, 8, NM,
                                     nullptr, Qbf, ctrl);
  // sample G0 (rows 0..1023): G0s = img[:1024] @ W, writes G0sbf, a += ||G0s||^2
  gemm_bt<0><<<128, 256, 0, stream>>>(imgbf, Wt, NM, 16, NK,
                                      nullptr, G0sbf, ctrl);
  // sample P: P_s = G0s @ W^T, b += ||P_s||^2 (no writes)
  gemm_bt<1><<<64, 256, 0, stream>>>(G0sbf, Wbf, NK, 8, NM,
                                     nullptr, nullptr, ctrl);

  solve_k<<<1, 1, 0, stream>>>(ctrl);

  // r = alpha * (img @ W) : [8192x2048], KK=1024, scaled f32 epilogue
  gemm_bt<3><<<1024, 256, 0, stream>>>(imgbf, Wt, NM, 16, NK,
                                       Rr, nullptr, ctrl);
  // pred = alpha * (img @ Q) : [8192x1024], KK=1024 (Q symmetric -> B^T rows = Q rows)
  gemm_bt<3><<<512, 256, 0, stream>>>(imgbf, Qbf, NM, 8, NM,
                                      Pp, nullptr, ctrl);
}

// Round 5
// 211.905 us; speedup vs baseline: 1.0974x; 1.0974x over previous
//
#include <hip/hip_runtime.h>

// ---- problem constants ----
#define NB 8192      // batch rows
#define NM 1024      // image dim
#define NK 2048      // dictionary size

typedef unsigned short ushort_t;
using bf16x8 = __attribute__((ext_vector_type(8))) short;
using f32x4  = __attribute__((ext_vector_type(4))) float;

struct Ctrl { double a; double b; int T; float alpha; };

__device__ __forceinline__ ushort_t f2bf(float f) {
  union { float f; unsigned u; } v; v.f = f;
  unsigned r = (v.u + 0x7FFFu + ((v.u >> 16) & 1u)) >> 16;  // RNE
  return (ushort_t)r;
}

__device__ __forceinline__ void gload_lds16(const void* g, void* l) {
  __builtin_amdgcn_global_load_lds(
      (const __attribute__((address_space(1))) unsigned int*)g,
      (__attribute__((address_space(3))) unsigned int*)l, 16, 0, 0);
}

// ======================= small 128^2 m97-style GEMM (samples) ================
// C = Aop * Bop^T. MODE 0: write bf16 C + reduce ||C||^2 -> ctrl->a
//                  MODE 1: no writes,      reduce ||C||^2 -> ctrl->b
template<int MODE>
__global__ __launch_bounds__(256)
void gemm_bt(const ushort_t* __restrict__ Aop, const ushort_t* __restrict__ Bop,
             int KK, int njb, int outld,
             ushort_t* __restrict__ outbf, Ctrl* __restrict__ ctrl)
{
  const int tid = threadIdx.x;
  const int w = tid >> 6, l = tid & 63;
  const int wm = w >> 1, wn = w & 1;
  const int bi = blockIdx.x / njb, bj = blockIdx.x % njb;
  const int i0 = bi * 128, j0 = bj * 128;
  const int l15 = l & 15, l16 = l >> 4;
  const int lr = l >> 3;
  const int lc = (l & 7) * 8;

  __shared__ __align__(128) ushort_t As[128 * 64];
  __shared__ __align__(128) ushort_t Bs[128 * 64];
  __shared__ double red[4];

  f32x4 acc[4][4];
#pragma unroll
  for (int m = 0; m < 4; ++m)
#pragma unroll
    for (int n = 0; n < 4; ++n)
      acc[m][n] = (f32x4){0.f, 0.f, 0.f, 0.f};

  for (int k0 = 0; k0 < KK; k0 += 64) {
#pragma unroll
    for (int c = 0; c < 4; ++c) {
      const int rr = c * 32 + w * 8 + lr;
      const ushort_t* ga = Aop + ((size_t)(i0 + rr) * (size_t)KK + k0 + lc);
      const ushort_t* gb = Bop + ((size_t)(j0 + rr) * (size_t)KK + k0 + lc);
      const int base = w * 512 + c * 2048;
      gload_lds16(ga, &As[base]);
      gload_lds16(gb, &Bs[base]);
    }
    __syncthreads();
#pragma unroll
    for (int ks = 0; ks < 2; ++ks) {
      bf16x8 af[4], bfr[4];
#pragma unroll
      for (int m = 0; m < 4; ++m)
        af[m] = *(const bf16x8*)&As[(wm * 64 + m * 16 + l15) * 64 + ks * 32 + l16 * 8];
#pragma unroll
      for (int n = 0; n < 4; ++n)
        bfr[n] = *(const bf16x8*)&Bs[(wn * 64 + n * 16 + l15) * 64 + ks * 32 + l16 * 8];
#pragma unroll
      for (int m = 0; m < 4; ++m)
#pragma unroll
        for (int n = 0; n < 4; ++n)
          acc[m][n] = __builtin_amdgcn_mfma_f32_16x16x32_bf16(af[m], bfr[n], acc[m][n], 0, 0, 0);
    }
    __syncthreads();
  }

  double sq = 0.0;
#pragma unroll
  for (int m = 0; m < 4; ++m)
#pragma unroll
    for (int n = 0; n < 4; ++n) {
      const int gr0 = i0 + wm * 64 + m * 16 + l16 * 4;
      const int gc  = j0 + wn * 64 + n * 16 + l15;
#pragma unroll
      for (int q = 0; q < 4; ++q) {
        const size_t idx = (size_t)(gr0 + q) * (size_t)outld + gc;
        const float v = acc[m][n][q];
        if constexpr (MODE == 0) outbf[idx] = f2bf(v);
        sq += (double)v * (double)v;
      }
    }
#pragma unroll
  for (int off = 32; off > 0; off >>= 1) sq += __shfl_down(sq, off, 64);
  if (l == 0) red[w] = sq;
  __syncthreads();
  if (tid == 0) {
    const double tot = red[0] + red[1] + red[2] + red[3];
    if constexpr (MODE == 0) atomicAdd(&ctrl->a, tot);
    else                     atomicAdd(&ctrl->b, tot);
  }
}

// ================== 256^2 8-wave deep-pipelined GEMM (finals) ================
// C = Aop * Bop^T, 256x256 tile, BK=64, 512 threads (8 waves, 2Mx4N).
// LDS: 2 x (A 256x64 + B 256x64) bf16 = 128 KiB, double-buffered, counted vmcnt.
// XOR swizzle (row&7)<<4 on byte col: inverse-swizzled global src, swizzled read.
// MODE 0: outf = alpha*C (f32) AND outbf = bf16(C)   (r-final, G0 capture)
// MODE 1: outf = alpha*C (f32)                        (pred-final)
template<int MODE>
__global__ __launch_bounds__(512, 2)
void gemm256(const ushort_t* __restrict__ Aop, const ushort_t* __restrict__ Bop,
             int KK, int njb, int outld,
             float* __restrict__ outf, ushort_t* __restrict__ outbf,
             const Ctrl* __restrict__ ctrl)
{
  const int tid = threadIdx.x;
  const int w = tid >> 6, l = tid & 63;
  const int wm = w >> 2, wn = w & 3;          // 2 x 4 wave grid
  const int bi = blockIdx.x / njb, bj = blockIdx.x % njb;
  const int i0 = bi * 256, j0 = bj * 256;
  const int l15 = l & 15, l16 = l >> 4;

  const float al = ctrl->alpha;

  // [buf][A=0/B=1][256 rows][64 cols] bf16, 128 KiB total
  __shared__ __align__(1024) ushort_t lds[2][2][256 * 64];

  // staging invariants: thread covers row rA (of each 64-row round), 16B chunk
  const int rA = tid >> 3;                         // 0..63
  const int cbl = (tid & 7) << 4;                  // linear byte col 0..112
  const int scol = (cbl ^ ((rA & 7) << 4)) >> 1;   // inverse-swizzled src col (elems)

  // read-side swizzled cols (elems) for ks=0/1; key depends on row&7 = l15&7
  const int kx = (l15 & 7) << 4;
  const int rc0 = ((0 * 64 + l16 * 16) ^ kx) >> 1;
  const int rc1 = ((1 * 64 + l16 * 16) ^ kx) >> 1;

  f32x4 acc[8][4];
#pragma unroll
  for (int m = 0; m < 8; ++m)
#pragma unroll
    for (int n = 0; n < 4; ++n)
      acc[m][n] = (f32x4){0.f, 0.f, 0.f, 0.f};

#define STAGE256(buf, kt) do {                                                  \
    const ushort_t* _a = Aop + (size_t)(i0 + rA) * (size_t)KK + (kt) * 64 + scol; \
    const ushort_t* _b = Bop + (size_t)(j0 + rA) * (size_t)KK + (kt) * 64 + scol; \
    _Pragma("unroll")                                                           \
    for (int c = 0; c < 4; ++c) {                                               \
      gload_lds16(_a + (size_t)(c * 64) * (size_t)KK, &lds[buf][0][c * 4096 + w * 512]); \
      gload_lds16(_b + (size_t)(c * 64) * (size_t)KK, &lds[buf][1][c * 4096 + w * 512]); \
    }                                                                           \
  } while (0)

  const int nt = KK >> 6;                     // K-tiles (>=2 for all our calls)
  STAGE256(0, 0);
  STAGE256(1, 1);

  for (int t = 0; t < nt; ++t) {
    const int cur = t & 1;
    if (t + 1 < nt) asm volatile("s_waitcnt vmcnt(8)" ::: "memory");
    else            asm volatile("s_waitcnt vmcnt(0)" ::: "memory");
    __builtin_amdgcn_s_barrier();

    // B fragments for the whole tile (4n x 2ks), kept in regs
    bf16x8 Bf[4][2];
#pragma unroll
    for (int n = 0; n < 4; ++n) {
      const int br = (wn * 64 + n * 16 + l15) * 64;
      Bf[n][0] = *(const bf16x8*)&lds[cur][1][br + rc0];
      Bf[n][1] = *(const bf16x8*)&lds[cur][1][br + rc1];
    }
    // 4 phases x (2m x 4n x 2ks = 16 MFMA)
#pragma unroll
    for (int ph = 0; ph < 4; ++ph) {
      bf16x8 Af[2][2];
#pragma unroll
      for (int mm = 0; mm < 2; ++mm) {
        const int ar = (wm * 128 + (ph * 2 + mm) * 16 + l15) * 64;
        Af[mm][0] = *(const bf16x8*)&lds[cur][0][ar + rc0];
        Af[mm][1] = *(const bf16x8*)&lds[cur][0][ar + rc1];
      }
      __builtin_amdgcn_s_setprio(1);
#pragma unroll
      for (int mm = 0; mm < 2; ++mm)
#pragma unroll
        for (int n = 0; n < 4; ++n) {
          acc[ph * 2 + mm][n] = __builtin_amdgcn_mfma_f32_16x16x32_bf16(
              Af[mm][0], Bf[n][0], acc[ph * 2 + mm][n], 0, 0, 0);
          acc[ph * 2 + mm][n] = __builtin_amdgcn_mfma_f32_16x16x32_bf16(
              Af[mm][1], Bf[n][1], acc[ph * 2 + mm][n], 0, 0, 0);
        }
      __builtin_amdgcn_s_setprio(0);
    }

    __builtin_amdgcn_s_barrier();             // all waves done reading buf[cur]
    if (t + 2 < nt) STAGE256(cur, t + 2);     // overwrite it for tile t+2
  }
#undef STAGE256

  // epilogue: C/D frag layout col = lane&15, row = (lane>>4)*4 + q
#pragma unroll
  for (int m = 0; m < 8; ++m)
#pragma unroll
    for (int n = 0; n < 4; ++n) {
      const int gr0 = i0 + wm * 128 + m * 16 + l16 * 4;
      const int gc  = j0 + wn * 64 + n * 16 + l15;
#pragma unroll
      for (int q = 0; q < 4; ++q) {
        const size_t idx = (size_t)(gr0 + q) * (size_t)outld + gc;
        const float v = acc[m][n][q];
        outf[idx] = al * v;
        if constexpr (MODE == 0) outbf[idx] = f2bf(v);
      }
    }
}

// ============================ conversions ====================================
__global__ void conv_img_k(const float* __restrict__ src, ushort_t* __restrict__ dst) {
  int i = blockIdx.x * blockDim.x + threadIdx.x;
  const int stride = gridDim.x * blockDim.x;
  const int n4 = (NB * NM) / 4;
  for (; i < n4; i += stride) {
    const float4 v = ((const float4*)src)[i];
    ushort4 o;
    o.x = f2bf(v.x); o.y = f2bf(v.y); o.z = f2bf(v.z); o.w = f2bf(v.w);
    ((ushort4*)dst)[i] = o;
  }
}

__global__ void conv_w_k(const float* __restrict__ W, ushort_t* __restrict__ Wbf,
                         ushort_t* __restrict__ Wt) {
  int i = blockIdx.x * blockDim.x + threadIdx.x;
  const int stride = gridDim.x * blockDim.x;
  for (; i < NM * NK; i += stride) {
    const ushort_t v = f2bf(W[i]);
    Wbf[i] = v;
    const int m = i >> 11, k = i & (NK - 1);
    Wt[k * NM + m] = v;
  }
}

// Scalar recurrence in the Krylov basis {G0, G0*A}: homogeneous in (a,b),
// so sampled norms (any common scale) are valid inputs.
__global__ void solve_k(Ctrl* c) {
  const double s = 0.1 * (2.0 / 8388608.0);
  const double a = c->a, b = c->b;
  int T = 10000;
  for (int t = 1; t <= 10000; ++t) {
    const double ap = (double)(t - 1) * s;
    const double bp = -s * s * (double)(t - 1) * (double)(t - 2) * 0.5;
    const double num = s * s * (a - 2.0 * ap * b);
    const double den = ap * ap * a + 2.0 * ap * bp * b;
    if (den > 0.0 && num < 1e-4 * den) { T = t; break; }
  }
  c->T = T;
  c->alpha = (float)((double)T * s);
}

extern "C" void kernel_launch(void* const* d_in, const int* in_sizes, int n_in,
                              void* d_out, int out_size, void* d_ws, size_t ws_size,
                              hipStream_t stream) {
  (void)in_sizes; (void)n_in; (void)out_size; (void)ws_size;
  const float* img = (const float*)d_in[0];   // [8192][1024] f32
  const float* W   = (const float*)d_in[1];   // [1024][2048] f32, cols unit-norm

  float* Rr = (float*)d_out;                   // r = alpha*G0, f32 [8192][2048]
  float* Pp = Rr + (size_t)NB * NK;            // pred = alpha*(G0 @ W^T), f32 [8192][1024]

  char* ws = (char*)d_ws;
  ushort_t* imgbf = (ushort_t*)(ws + 0);          // 16,777,216 B [8192][1024]
  ushort_t* Wt    = (ushort_t*)(ws + 16777216);   //  4,194,304 B [2048][1024]
  ushort_t* Wbf   = (ushort_t*)(ws + 20971520);   //  4,194,304 B [1024][2048]
  ushort_t* G0sbf = (ushort_t*)(ws + 25165824);   //  1,048,576 B [256][2048] sample
  ushort_t* G0bf  = (ushort_t*)(ws + 26214400);   // 33,554,432 B [8192][2048]
  Ctrl*     ctrl  = (Ctrl*)(ws + 59768832);

  (void)hipMemsetAsync(ctrl, 0, sizeof(Ctrl), stream);

  conv_img_k<<<2048, 256, 0, stream>>>(img, imgbf);
  conv_w_k<<<512, 256, 0, stream>>>(W, Wbf, Wt);

  // sample a: G0s = img[0:256] @ W  -> G0sbf, a += ||G0s||^2   (32 blocks)
  gemm_bt<0><<<32, 256, 0, stream>>>(imgbf, Wt, NM, 16, NK, G0sbf, ctrl);
  // sample b: ||G0s @ W^T||^2 -> b                              (16 blocks)
  gemm_bt<1><<<16, 256, 0, stream>>>(G0sbf, Wbf, NK, 8, NM, nullptr, ctrl);

  solve_k<<<1, 1, 0, stream>>>(ctrl);

  // r = alpha*(img @ W), also capture G0 bf16.  grid 32x8 = 256 blocks.
  gemm256<0><<<256, 512, 0, stream>>>(imgbf, Wt, NM, 8, NK, Rr, G0bf, ctrl);
  // pred = alpha*(G0 @ W^T).  grid 32x4 = 128 blocks.
  gemm256<1><<<128, 512, 0, stream>>>(G0bf, Wbf, NK, 4, NM, Pp, nullptr, ctrl);
}

// Round 6
// 195.861 us; speedup vs baseline: 1.1872x; 1.0819x over previous
//
#include <hip/hip_runtime.h>

// ---- problem constants ----
#define NB 8192      // batch rows
#define NM 1024      // image dim
#define NK 2048      // dictionary size

typedef unsigned short ushort_t;
using bf16x8 = __attribute__((ext_vector_type(8))) short;
using f32x4  = __attribute__((ext_vector_type(4))) float;

struct Ctrl { double a; double b; int T; float alpha; };

__device__ __forceinline__ ushort_t f2bf(float f) {
  union { float f; unsigned u; } v; v.f = f;
  unsigned r = (v.u + 0x7FFFu + ((v.u >> 16) & 1u)) >> 16;  // RNE
  return (ushort_t)r;
}

__device__ __forceinline__ void gload_lds16(const void* g, void* l) {
  __builtin_amdgcn_global_load_lds(
      (const __attribute__((address_space(1))) unsigned int*)g,
      (__attribute__((address_space(3))) unsigned int*)l, 16, 0, 0);
}

// ======================= small 128^2 m97-style GEMM (samples) ================
// C = Aop * Bop^T. MODE 0: write bf16 C + reduce ||C||^2 -> ctrl->a
//                  MODE 1: no writes,      reduce ||C||^2 -> ctrl->b
template<int MODE>
__global__ __launch_bounds__(256)
void gemm_bt(const ushort_t* __restrict__ Aop, const ushort_t* __restrict__ Bop,
             int KK, int njb, int outld,
             ushort_t* __restrict__ outbf, Ctrl* __restrict__ ctrl)
{
  const int tid = threadIdx.x;
  const int w = tid >> 6, l = tid & 63;
  const int wm = w >> 1, wn = w & 1;
  const int bi = blockIdx.x / njb, bj = blockIdx.x % njb;
  const int i0 = bi * 128, j0 = bj * 128;
  const int l15 = l & 15, l16 = l >> 4;
  const int lr = l >> 3;
  const int lc = (l & 7) * 8;

  __shared__ __align__(128) ushort_t As[128 * 64];
  __shared__ __align__(128) ushort_t Bs[128 * 64];
  __shared__ double red[4];

  f32x4 acc[4][4];
#pragma unroll
  for (int m = 0; m < 4; ++m)
#pragma unroll
    for (int n = 0; n < 4; ++n)
      acc[m][n] = (f32x4){0.f, 0.f, 0.f, 0.f};

  for (int k0 = 0; k0 < KK; k0 += 64) {
#pragma unroll
    for (int c = 0; c < 4; ++c) {
      const int rr = c * 32 + w * 8 + lr;
      const ushort_t* ga = Aop + ((size_t)(i0 + rr) * (size_t)KK + k0 + lc);
      const ushort_t* gb = Bop + ((size_t)(j0 + rr) * (size_t)KK + k0 + lc);
      const int base = w * 512 + c * 2048;
      gload_lds16(ga, &As[base]);
      gload_lds16(gb, &Bs[base]);
    }
    __syncthreads();
#pragma unroll
    for (int ks = 0; ks < 2; ++ks) {
      bf16x8 af[4], bfr[4];
#pragma unroll
      for (int m = 0; m < 4; ++m)
        af[m] = *(const bf16x8*)&As[(wm * 64 + m * 16 + l15) * 64 + ks * 32 + l16 * 8];
#pragma unroll
      for (int n = 0; n < 4; ++n)
        bfr[n] = *(const bf16x8*)&Bs[(wn * 64 + n * 16 + l15) * 64 + ks * 32 + l16 * 8];
#pragma unroll
      for (int m = 0; m < 4; ++m)
#pragma unroll
        for (int n = 0; n < 4; ++n)
          acc[m][n] = __builtin_amdgcn_mfma_f32_16x16x32_bf16(af[m], bfr[n], acc[m][n], 0, 0, 0);
    }
    __syncthreads();
  }

  double sq = 0.0;
#pragma unroll
  for (int m = 0; m < 4; ++m)
#pragma unroll
    for (int n = 0; n < 4; ++n) {
      const int gr0 = i0 + wm * 64 + m * 16 + l16 * 4;
      const int gc  = j0 + wn * 64 + n * 16 + l15;
#pragma unroll
      for (int q = 0; q < 4; ++q) {
        const size_t idx = (size_t)(gr0 + q) * (size_t)outld + gc;
        const float v = acc[m][n][q];
        if constexpr (MODE == 0) outbf[idx] = f2bf(v);
        sq += (double)v * (double)v;
      }
    }
#pragma unroll
  for (int off = 32; off > 0; off >>= 1) sq += __shfl_down(sq, off, 64);
  if (l == 0) red[w] = sq;
  __syncthreads();
  if (tid == 0) {
    const double tot = red[0] + red[1] + red[2] + red[3];
    if constexpr (MODE == 0) atomicAdd(&ctrl->a, tot);
    else                     atomicAdd(&ctrl->b, tot);
  }
}

// ============== 256xBN 8-phase deep-pipelined GEMM (finals) ==================
// C = Aop * Bop^T, tile 256xBN, BK=64, 512 threads (8 waves, 2Mx4N).
// Per 2-K-tile iter: 8 phases {ds_read subtile | stage 1 half-tile | barrier |
// lgkmcnt(0) | setprio+MFMA | barrier}; counted vmcnt at ph4/ph8 only.
// Stage slots: ph1,2: buf1.A<-t+1; ph3,4: buf0.B<-t+2; ph5,6: buf0.A<-t+2;
//              ph7,8: buf1.B<-t+3.  (B is register-cached at ph1/ph5 -> dead.)
// XOR swizzle byte^=(row&7)<<4 : inverse-swizzled global src, swizzled ds_read.
// MODE 0: outf = alpha*C (f32) AND outbf = bf16(C);  MODE 1: outf = alpha*C.
template<int MODE, int BN>
__global__ __launch_bounds__(512, 2)
void gemm8ph(const ushort_t* __restrict__ Aop, const ushort_t* __restrict__ Bop,
             int KK, int njb, int outld,
             float* __restrict__ outf, ushort_t* __restrict__ outbf,
             const Ctrl* __restrict__ ctrl)
{
  constexpr int WN  = BN / 4;    // wave N extent (64 or 32)
  constexpr int NFR = BN / 64;   // B frags per wave (4 or 2)

  const int tid = threadIdx.x;
  const int w = tid >> 6, l = tid & 63;
  const int wm = w >> 2, wn = w & 3;
  // XCD-aware swizzle (grid % 8 == 0)
  const int wg = (blockIdx.x & 7) * ((int)gridDim.x >> 3) + ((int)blockIdx.x >> 3);
  const int bi = wg / njb, bj = wg % njb;
  const int i0 = bi * 256, j0 = bj * BN;
  const int l15 = l & 15, l16 = l >> 4;
  const int srow8 = l >> 3;          // lane row-in-8 for staging
  const int scb   = (l & 7) << 4;    // lane byte col for staging

  __shared__ __align__(1024) ushort_t ldsA[2][256 * 64];
  __shared__ __align__(1024) ushort_t ldsB[2][BN * 64];

  f32x4 acc[8][NFR];
#pragma unroll
  for (int m = 0; m < 8; ++m)
#pragma unroll
    for (int n = 0; n < NFR; ++n)
      acc[m][n] = (f32x4){0.f, 0.f, 0.f, 0.f};
  bf16x8 Bf[NFR][2];

  auto SH2 = [&](ushort_t* lb, const ushort_t* g0) {   // 128-row half, 2 calls/wave
#pragma unroll
    for (int c = 0; c < 2; ++c) {
      const int row = (w * 2 + c) * 8 + srow8;
      const int sc = (scb ^ ((row & 7) << 4)) >> 1;
      gload_lds16(g0 + (size_t)row * (size_t)KK + sc, lb + (w * 2 + c) * 512);
    }
  };
  auto SH1 = [&](ushort_t* lb, const ushort_t* g0) {   // 64-row half, 1 call/wave
    const int row = w * 8 + srow8;
    const int sc = (scb ^ ((row & 7) << 4)) >> 1;
    gload_lds16(g0 + (size_t)row * (size_t)KK + sc, lb + w * 512);
  };
  auto stA = [&](int buf, int half, int kt) {
    SH2(&ldsA[buf][half * (128 * 64)],
        Aop + (size_t)(i0 + half * 128) * (size_t)KK + (size_t)kt * 64);
  };
  auto stB = [&](int buf, int half, int kt) {
    if constexpr (BN == 256)
      SH2(&ldsB[buf][half * (128 * 64)],
          Bop + (size_t)(j0 + half * 128) * (size_t)KK + (size_t)kt * 64);
    else
      SH1(&ldsB[buf][half * (64 * 64)],
          Bop + (size_t)(j0 + half * 64) * (size_t)KK + (size_t)kt * 64);
  };
  auto rdA = [&](int buf, int R, int ks) -> bf16x8 {
    const int bc = ((ks * 64 + l16 * 16) ^ ((R & 7) << 4)) >> 1;
    return *(const bf16x8*)&ldsA[buf][R * 64 + bc];
  };
  auto rdB = [&](int buf, int R, int ks) -> bf16x8 {
    const int bc = ((ks * 64 + l16 * 16) ^ ((R & 7) << 4)) >> 1;
    return *(const bf16x8*)&ldsB[buf][R * 64 + bc];
  };

#define VMC_STEADY() do { \
    if constexpr (BN == 256) asm volatile("s_waitcnt vmcnt(4)" ::: "memory"); \
    else                     asm volatile("s_waitcnt vmcnt(2)" ::: "memory"); } while (0)

  // PHASE: LB=load Bf from bufc; STG=stage stmt; VM: 0 none, 1 steady, 2 drain
#define PHASE(bufc, q, LB, STG, VM)                                         \
  do {                                                                      \
    if (LB) {                                                               \
      _Pragma("unroll")                                                     \
      for (int n = 0; n < NFR; ++n) {                                       \
        Bf[n][0] = rdB(bufc, wn * WN + n * 16 + l15, 0);                    \
        Bf[n][1] = rdB(bufc, wn * WN + n * 16 + l15, 1);                    \
      }                                                                     \
    }                                                                       \
    bf16x8 a00 = rdA(bufc, wm * 128 + ((q) * 2 + 0) * 16 + l15, 0);         \
    bf16x8 a01 = rdA(bufc, wm * 128 + ((q) * 2 + 0) * 16 + l15, 1);         \
    bf16x8 a10 = rdA(bufc, wm * 128 + ((q) * 2 + 1) * 16 + l15, 0);         \
    bf16x8 a11 = rdA(bufc, wm * 128 + ((q) * 2 + 1) * 16 + l15, 1);         \
    STG;                                                                    \
    __builtin_amdgcn_s_barrier();                                           \
    asm volatile("s_waitcnt lgkmcnt(0)" ::: "memory");                      \
    __builtin_amdgcn_sched_barrier(0);                                      \
    __builtin_amdgcn_s_setprio(1);                                          \
    _Pragma("unroll")                                                       \
    for (int n = 0; n < NFR; ++n) {                                         \
      acc[(q) * 2 + 0][n] = __builtin_amdgcn_mfma_f32_16x16x32_bf16(        \
          a00, Bf[n][0], acc[(q) * 2 + 0][n], 0, 0, 0);                     \
      acc[(q) * 2 + 0][n] = __builtin_amdgcn_mfma_f32_16x16x32_bf16(        \
          a01, Bf[n][1], acc[(q) * 2 + 0][n], 0, 0, 0);                     \
      acc[(q) * 2 + 1][n] = __builtin_amdgcn_mfma_f32_16x16x32_bf16(        \
          a10, Bf[n][0], acc[(q) * 2 + 1][n], 0, 0, 0);                     \
      acc[(q) * 2 + 1][n] = __builtin_amdgcn_mfma_f32_16x16x32_bf16(        \
          a11, Bf[n][1], acc[(q) * 2 + 1][n], 0, 0, 0);                     \
    }                                                                       \
    __builtin_amdgcn_s_setprio(0);                                          \
    {                                                                       \
      const int _vm = (VM);                                                 \
      if (_vm == 1) VMC_STEADY();                                           \
      else if (_vm == 2) asm volatile("s_waitcnt vmcnt(0)" ::: "memory");   \
    }                                                                       \
    __builtin_amdgcn_s_barrier();                                           \
    __builtin_amdgcn_sched_barrier(0);                                      \
  } while (0)

  const int nt = KK >> 6;        // K-tiles (even, >= 4)
  const int nit = nt >> 1;

  // prologue: buf0 <- tile0 (A+B), buf1.B <- tile1
  stA(0, 0, 0); stA(0, 1, 0); stB(0, 0, 0); stB(0, 1, 0);
  stB(1, 0, 1); stB(1, 1, 1);
  VMC_STEADY();
  __builtin_amdgcn_s_barrier();
  __builtin_amdgcn_sched_barrier(0);

#pragma unroll 1
  for (int it = 0; it < nit; ++it) {
    const int t1 = 2 * it + 1, t2 = 2 * it + 2, t3 = 2 * it + 3;
    const bool s2 = t2 < nt, s3 = t3 < nt;
    PHASE(0, 0, true,  { stA(1, 0, t1); },            0);            // ph1
    PHASE(0, 1, false, { stA(1, 1, t1); },            0);            // ph2
    PHASE(0, 2, false, { if (s2) stB(0, 0, t2); },    0);            // ph3
    PHASE(0, 3, false, { if (s2) stB(0, 1, t2); },    s2 ? 1 : 2);   // ph4
    PHASE(1, 0, true,  { if (s2) stA(0, 0, t2); },    0);            // ph5
    PHASE(1, 1, false, { if (s2) stA(0, 1, t2); },    0);            // ph6
    PHASE(1, 2, false, { if (s3) stB(1, 0, t3); },    0);            // ph7
    PHASE(1, 3, false, { if (s3) stB(1, 1, t3); },    (it + 1 < nit) ? 1 : 0); // ph8
  }
#undef PHASE
#undef VMC_STEADY

  // epilogue: C/D frag layout col = lane&15, row = (lane>>4)*4 + q
  const float al = ctrl->alpha;
#pragma unroll
  for (int m = 0; m < 8; ++m)
#pragma unroll
    for (int n = 0; n < NFR; ++n) {
      const int gr0 = i0 + wm * 128 + m * 16 + l16 * 4;
      const int gc  = j0 + wn * WN + n * 16 + l15;
#pragma unroll
      for (int q = 0; q < 4; ++q) {
        const size_t idx = (size_t)(gr0 + q) * (size_t)outld + gc;
        const float v = acc[m][n][q];
        outf[idx] = al * v;
        if constexpr (MODE == 0) outbf[idx] = f2bf(v);
      }
    }
}

// ============================ conversions ====================================
__global__ void conv_img_k(const float* __restrict__ src, ushort_t* __restrict__ dst) {
  int i = blockIdx.x * blockDim.x + threadIdx.x;
  const int stride = gridDim.x * blockDim.x;
  const int n4 = (NB * NM) / 4;
  for (; i < n4; i += stride) {
    const float4 v = ((const float4*)src)[i];
    ushort4 o;
    o.x = f2bf(v.x); o.y = f2bf(v.y); o.z = f2bf(v.z); o.w = f2bf(v.w);
    ((ushort4*)dst)[i] = o;
  }
}

__global__ void conv_w_k(const float* __restrict__ W, ushort_t* __restrict__ Wbf,
                         ushort_t* __restrict__ Wt) {
  int i = blockIdx.x * blockDim.x + threadIdx.x;
  const int stride = gridDim.x * blockDim.x;
  for (; i < NM * NK; i += stride) {
    const ushort_t v = f2bf(W[i]);
    Wbf[i] = v;
    const int m = i >> 11, k = i & (NK - 1);
    Wt[k * NM + m] = v;
  }
}

// Scalar recurrence in the Krylov basis {G0, G0*A}: homogeneous in (a,b),
// so sampled norms (any common scale) are valid inputs.
__global__ void solve_k(Ctrl* c) {
  const double s = 0.1 * (2.0 / 8388608.0);
  const double a = c->a, b = c->b;
  int T = 10000;
  for (int t = 1; t <= 10000; ++t) {
    const double ap = (double)(t - 1) * s;
    const double bp = -s * s * (double)(t - 1) * (double)(t - 2) * 0.5;
    const double num = s * s * (a - 2.0 * ap * b);
    const double den = ap * ap * a + 2.0 * ap * bp * b;
    if (den > 0.0 && num < 1e-4 * den) { T = t; break; }
  }
  c->T = T;
  c->alpha = (float)((double)T * s);
}

extern "C" void kernel_launch(void* const* d_in, const int* in_sizes, int n_in,
                              void* d_out, int out_size, void* d_ws, size_t ws_size,
                              hipStream_t stream) {
  (void)in_sizes; (void)n_in; (void)out_size; (void)ws_size;
  const float* img = (const float*)d_in[0];   // [8192][1024] f32
  const float* W   = (const float*)d_in[1];   // [1024][2048] f32, cols unit-norm

  float* Rr = (float*)d_out;                   // r = alpha*G0, f32 [8192][2048]
  float* Pp = Rr + (size_t)NB * NK;            // pred = alpha*(G0 @ W^T), f32 [8192][1024]

  char* ws = (char*)d_ws;
  ushort_t* imgbf = (ushort_t*)(ws + 0);          // 16,777,216 B [8192][1024]
  ushort_t* Wt    = (ushort_t*)(ws + 16777216);   //  4,194,304 B [2048][1024]
  ushort_t* Wbf   = (ushort_t*)(ws + 20971520);   //  4,194,304 B [1024][2048]
  ushort_t* G0sbf = (ushort_t*)(ws + 25165824);   //  1,048,576 B [256][2048] sample
  ushort_t* G0bf  = (ushort_t*)(ws + 26214400);   // 33,554,432 B [8192][2048]
  Ctrl*     ctrl  = (Ctrl*)(ws + 59768832);

  (void)hipMemsetAsync(ctrl, 0, sizeof(Ctrl), stream);

  conv_img_k<<<2048, 256, 0, stream>>>(img, imgbf);
  conv_w_k<<<512, 256, 0, stream>>>(W, Wbf, Wt);

  // sample a: G0s = img[0:256] @ W  -> G0sbf, a += ||G0s||^2   (32 blocks)
  gemm_bt<0><<<32, 256, 0, stream>>>(imgbf, Wt, NM, 16, NK, G0sbf, ctrl);
  // sample b: ||G0s @ W^T||^2 -> b                              (16 blocks)
  gemm_bt<1><<<16, 256, 0, stream>>>(G0sbf, Wbf, NK, 8, NM, nullptr, ctrl);

  solve_k<<<1, 1, 0, stream>>>(ctrl);

  // r = alpha*(img @ W), also capture G0 bf16.  grid 32x8 = 256 blocks, BN=256.
  gemm8ph<0, 256><<<256, 512, 0, stream>>>(imgbf, Wt, NM, 8, NK, Rr, G0bf, ctrl);
  // pred = alpha*(G0 @ W^T).  grid 32x8 = 256 blocks, BN=128 (full GPU).
  gemm8ph<1, 128><<<256, 512, 0, stream>>>(G0bf, Wbf, NK, 8, NM, Pp, nullptr, ctrl);
}

// Round 7
// 174.379 us; speedup vs baseline: 1.3335x; 1.1232x over previous
//
#include <hip/hip_runtime.h>

// ---- problem constants ----
#define NB 8192      // batch rows
#define NM 1024      // image dim
#define NK 2048      // dictionary size

typedef unsigned short ushort_t;
using bf16x8 = __attribute__((ext_vector_type(8))) short;
using f32x4  = __attribute__((ext_vector_type(4))) float;

struct Ctrl { double a; double b; int done; int T; float alpha; };

__device__ __forceinline__ ushort_t f2bf(float f) {
  union { float f; unsigned u; } v; v.f = f;
  unsigned r = (v.u + 0x7FFFu + ((v.u >> 16) & 1u)) >> 16;  // RNE
  return (ushort_t)r;
}

__device__ __forceinline__ void gload_lds16(const void* g, void* l) {
  __builtin_amdgcn_global_load_lds(
      (const __attribute__((address_space(1))) unsigned int*)g,
      (__attribute__((address_space(3))) unsigned int*)l, 16, 0, 0);
}

// ============ fused prep: img->bf16, W->Wbf + tiled-transpose Wt, ctrl=0 =====
__global__ __launch_bounds__(256)
void conv_all_k(const float* __restrict__ img, const float* __restrict__ W,
                ushort_t* __restrict__ imgbf, ushort_t* __restrict__ Wbf,
                ushort_t* __restrict__ Wt, Ctrl* __restrict__ ctrl)
{
  const int tid = threadIdx.x;
  const int b = blockIdx.x;
  if (b < 512) {
    if (b == 0 && tid == 0) { ctrl->a = 0.0; ctrl->b = 0.0; ctrl->done = 0; }
    const int base = b * 4096;
#pragma unroll
    for (int i = 0; i < 16; ++i) {
      const int idx = base + i * 256 + tid;
      const float4 v = ((const float4*)img)[idx];
      ushort4 o;
      o.x = f2bf(v.x); o.y = f2bf(v.y); o.z = f2bf(v.z); o.w = f2bf(v.w);
      ((ushort4*)imgbf)[idx] = o;
    }
  } else {
    __shared__ ushort_t tile[64][65];
    const int bW = b - 512;                       // 512 tiles: 16(m) x 32(k)
    const int m0 = (bW >> 5) * 64, k0 = (bW & 31) * 64;
    const int r = tid >> 2, q = tid & 3;
    ushort_t loc[16];
#pragma unroll
    for (int j = 0; j < 4; ++j) {
      const float4 v = *(const float4*)&W[(size_t)(m0 + r) * NK + k0 + q * 16 + j * 4];
      loc[j * 4 + 0] = f2bf(v.x); loc[j * 4 + 1] = f2bf(v.y);
      loc[j * 4 + 2] = f2bf(v.z); loc[j * 4 + 3] = f2bf(v.w);
    }
#pragma unroll
    for (int j = 0; j < 4; ++j) {
      ushort4 o;
      o.x = loc[j * 4 + 0]; o.y = loc[j * 4 + 1];
      o.z = loc[j * 4 + 2]; o.w = loc[j * 4 + 3];
      *(ushort4*)&Wbf[(size_t)(m0 + r) * NK + k0 + q * 16 + j * 4] = o;
    }
#pragma unroll
    for (int jj = 0; jj < 16; ++jj) tile[r][q * 16 + jj] = loc[jj];
    __syncthreads();
    const int kk = tid >> 2, qq = tid & 3;
#pragma unroll
    for (int j = 0; j < 4; ++j) {
      ushort4 o;
      o.x = tile[qq * 16 + j * 4 + 0][kk];
      o.y = tile[qq * 16 + j * 4 + 1][kk];
      o.z = tile[qq * 16 + j * 4 + 2][kk];
      o.w = tile[qq * 16 + j * 4 + 3][kk];
      *(ushort4*)&Wt[(size_t)(k0 + kk) * NM + m0 + qq * 16 + j * 4] = o;
    }
  }
}

// ======================= small 128^2 m97-style GEMM (samples) ================
// C = Aop * Bop^T. MODE 0: write bf16 C + reduce ||C||^2 -> ctrl->a
//                  MODE 1: reduce ||C||^2 -> ctrl->b; LAST block solves T,alpha
template<int MODE>
__global__ __launch_bounds__(256)
void gemm_bt(const ushort_t* __restrict__ Aop, const ushort_t* __restrict__ Bop,
             int KK, int njb, int outld,
             ushort_t* __restrict__ outbf, Ctrl* __restrict__ ctrl)
{
  const int tid = threadIdx.x;
  const int w = tid >> 6, l = tid & 63;
  const int wm = w >> 1, wn = w & 1;
  const int bi = blockIdx.x / njb, bj = blockIdx.x % njb;
  const int i0 = bi * 128, j0 = bj * 128;
  const int l15 = l & 15, l16 = l >> 4;
  const int lr = l >> 3;
  const int lc = (l & 7) * 8;

  __shared__ __align__(128) ushort_t As[128 * 64];
  __shared__ __align__(128) ushort_t Bs[128 * 64];
  __shared__ double red[4];

  f32x4 acc[4][4];
#pragma unroll
  for (int m = 0; m < 4; ++m)
#pragma unroll
    for (int n = 0; n < 4; ++n)
      acc[m][n] = (f32x4){0.f, 0.f, 0.f, 0.f};

  for (int k0 = 0; k0 < KK; k0 += 64) {
#pragma unroll
    for (int c = 0; c < 4; ++c) {
      const int rr = c * 32 + w * 8 + lr;
      const ushort_t* ga = Aop + ((size_t)(i0 + rr) * (size_t)KK + k0 + lc);
      const ushort_t* gb = Bop + ((size_t)(j0 + rr) * (size_t)KK + k0 + lc);
      const int base = w * 512 + c * 2048;
      gload_lds16(ga, &As[base]);
      gload_lds16(gb, &Bs[base]);
    }
    __syncthreads();
#pragma unroll
    for (int ks = 0; ks < 2; ++ks) {
      bf16x8 af[4], bfr[4];
#pragma unroll
      for (int m = 0; m < 4; ++m)
        af[m] = *(const bf16x8*)&As[(wm * 64 + m * 16 + l15) * 64 + ks * 32 + l16 * 8];
#pragma unroll
      for (int n = 0; n < 4; ++n)
        bfr[n] = *(const bf16x8*)&Bs[(wn * 64 + n * 16 + l15) * 64 + ks * 32 + l16 * 8];
#pragma unroll
      for (int m = 0; m < 4; ++m)
#pragma unroll
        for (int n = 0; n < 4; ++n)
          acc[m][n] = __builtin_amdgcn_mfma_f32_16x16x32_bf16(af[m], bfr[n], acc[m][n], 0, 0, 0);
    }
    __syncthreads();
  }

  double sq = 0.0;
#pragma unroll
  for (int m = 0; m < 4; ++m)
#pragma unroll
    for (int n = 0; n < 4; ++n) {
      const int gr0 = i0 + wm * 64 + m * 16 + l16 * 4;
      const int gc  = j0 + wn * 64 + n * 16 + l15;
#pragma unroll
      for (int q = 0; q < 4; ++q) {
        const size_t idx = (size_t)(gr0 + q) * (size_t)outld + gc;
        const float v = acc[m][n][q];
        if constexpr (MODE == 0) outbf[idx] = f2bf(v);
        sq += (double)v * (double)v;
      }
    }
#pragma unroll
  for (int off = 32; off > 0; off >>= 1) sq += __shfl_down(sq, off, 64);
  if (l == 0) red[w] = sq;
  __syncthreads();
  if (tid == 0) {
    const double tot = red[0] + red[1] + red[2] + red[3];
    if constexpr (MODE == 0) {
      atomicAdd(&ctrl->a, tot);
    } else {
      atomicAdd(&ctrl->b, tot);
      __threadfence();
      if (atomicAdd(&ctrl->done, 1) == (int)gridDim.x - 1) {
        __threadfence();
        const double a = atomicAdd(&ctrl->a, 0.0);
        const double b = atomicAdd(&ctrl->b, 0.0);
        // Krylov-basis recurrence: r_t = t*s*G0 - s^2 t(t-1)/2 * G0A;
        // homogeneous in (a,b) -> sampled norms valid.
        const double s = 0.1 * (2.0 / 8388608.0);
        int T = 10000;
        for (int t = 1; t <= 10000; ++t) {
          const double ap = (double)(t - 1) * s;
          const double bp = -s * s * (double)(t - 1) * (double)(t - 2) * 0.5;
          const double num = s * s * (a - 2.0 * ap * b);
          const double den = ap * ap * a + 2.0 * ap * bp * b;
          if (den > 0.0 && num < 1e-4 * den) { T = t; break; }
        }
        ctrl->T = T;
        ctrl->alpha = (float)((double)T * s);
      }
    }
  }
}

// ============== 256xBN 8-phase deep-pipelined GEMM (finals) ==================
// C = Aop * Bop^T, tile 256xBN, BK=64, 512 threads (8 waves, 2Mx4N).
// Steady iter (2 K-tiles): 8 phases {ds_read subtile | stage 1 half-tile |
// barrier | lgkmcnt(0) | setprio+16 MFMA | [vmcnt] | barrier}; counted vmcnt
// at ph4/ph8 only. Last iteration peeled: quadrant stores overlap ph5-8.
// XOR swizzle byte^=(row&7)<<4 : inverse-swizzled global src, swizzled ds_read.
// MODE 0: outf = alpha*C (f32) AND outbf = bf16(C);  MODE 1: outf = alpha*C.
template<int MODE, int BN>
__global__ __launch_bounds__(512, 2)
void gemm8ph(const ushort_t* __restrict__ Aop, const ushort_t* __restrict__ Bop,
             int KK, int njb, int outld,
             float* __restrict__ outf, ushort_t* __restrict__ outbf,
             const Ctrl* __restrict__ ctrl)
{
  constexpr int WN  = BN / 4;    // wave N extent (64 or 32)
  constexpr int NFR = BN / 64;   // B frags per wave (4 or 2)

  const int tid = threadIdx.x;
  const int w = tid >> 6, l = tid & 63;
  const int wm = w >> 2, wn = w & 3;
  // XCD-aware swizzle (grid % 8 == 0)
  const int wg = (blockIdx.x & 7) * ((int)gridDim.x >> 3) + ((int)blockIdx.x >> 3);
  const int bi = wg / njb, bj = wg % njb;
  const int i0 = bi * 256, j0 = bj * BN;
  const int l15 = l & 15, l16 = l >> 4;
  const int srow8 = l >> 3;          // lane row-in-8 for staging
  const int scb   = (l & 7) << 4;    // lane byte col for staging

  const float al = ctrl->alpha;      // ready before launch (solve done)

  __shared__ __align__(1024) ushort_t ldsA[2][256 * 64];
  __shared__ __align__(1024) ushort_t ldsB[2][BN * 64];

  f32x4 acc[8][NFR];
#pragma unroll
  for (int m = 0; m < 8; ++m)
#pragma unroll
    for (int n = 0; n < NFR; ++n)
      acc[m][n] = (f32x4){0.f, 0.f, 0.f, 0.f};
  bf16x8 Bf[NFR][2];

  auto SH2 = [&](ushort_t* lb, const ushort_t* g0) {   // 128-row half
#pragma unroll
    for (int c = 0; c < 2; ++c) {
      const int row = (w * 2 + c) * 8 + srow8;
      const int sc = (scb ^ ((row & 7) << 4)) >> 1;
      gload_lds16(g0 + (size_t)row * (size_t)KK + sc, lb + (w * 2 + c) * 512);
    }
  };
  auto SH1 = [&](ushort_t* lb, const ushort_t* g0) {   // 64-row half
    const int row = w * 8 + srow8;
    const int sc = (scb ^ ((row & 7) << 4)) >> 1;
    gload_lds16(g0 + (size_t)row * (size_t)KK + sc, lb + w * 512);
  };
  auto stA = [&](int buf, int half, int kt) {
    SH2(&ldsA[buf][half * (128 * 64)],
        Aop + (size_t)(i0 + half * 128) * (size_t)KK + (size_t)kt * 64);
  };
  auto stB = [&](int buf, int half, int kt) {
    if constexpr (BN == 256)
      SH2(&ldsB[buf][half * (128 * 64)],
          Bop + (size_t)(j0 + half * 128) * (size_t)KK + (size_t)kt * 64);
    else
      SH1(&ldsB[buf][half * (64 * 64)],
          Bop + (size_t)(j0 + half * 64) * (size_t)KK + (size_t)kt * 64);
  };
  auto rdA = [&](int buf, int R, int ks) -> bf16x8 {
    const int bc = ((ks * 64 + l16 * 16) ^ ((R & 7) << 4)) >> 1;
    return *(const bf16x8*)&ldsA[buf][R * 64 + bc];
  };
  auto rdB = [&](int buf, int R, int ks) -> bf16x8 {
    const int bc = ((ks * 64 + l16 * 16) ^ ((R & 7) << 4)) >> 1;
    return *(const bf16x8*)&ldsB[buf][R * 64 + bc];
  };

#define VMC_STEADY() do { \
    if constexpr (BN == 256) asm volatile("s_waitcnt vmcnt(4)" ::: "memory"); \
    else                     asm volatile("s_waitcnt vmcnt(2)" ::: "memory"); } while (0)

// store one C-quadrant (overlapped into peeled phases)
#define STOREQ(qd)                                                          \
  do {                                                                      \
    _Pragma("unroll")                                                       \
    for (int mm = 0; mm < 2; ++mm) {                                        \
      const int m = (qd) * 2 + mm;                                          \
      const int gr0 = i0 + wm * 128 + m * 16 + l16 * 4;                     \
      _Pragma("unroll")                                                     \
      for (int n = 0; n < NFR; ++n) {                                       \
        const int gc = j0 + wn * WN + n * 16 + l15;                         \
        _Pragma("unroll")                                                   \
        for (int qq = 0; qq < 4; ++qq) {                                    \
          const size_t idx = (size_t)(gr0 + qq) * (size_t)outld + gc;       \
          const float v = acc[m][n][qq];                                    \
          outf[idx] = al * v;                                               \
          if constexpr (MODE == 0) outbf[idx] = f2bf(v);                    \
        }                                                                   \
      }                                                                     \
    }                                                                       \
  } while (0)

  // PHASE: LB=load Bf from bufc; STG=stage stmt; VM: 0 none 1 steady 2 drain;
  // EPI = post-MFMA statement (stores)
#define PHASE(bufc, q, LB, STG, VM, EPI)                                    \
  do {                                                                      \
    if (LB) {                                                               \
      _Pragma("unroll")                                                     \
      for (int n = 0; n < NFR; ++n) {                                       \
        Bf[n][0] = rdB(bufc, wn * WN + n * 16 + l15, 0);                    \
        Bf[n][1] = rdB(bufc, wn * WN + n * 16 + l15, 1);                    \
      }                                                                     \
    }                                                                       \
    bf16x8 a00 = rdA(bufc, wm * 128 + ((q) * 2 + 0) * 16 + l15, 0);         \
    bf16x8 a01 = rdA(bufc, wm * 128 + ((q) * 2 + 0) * 16 + l15, 1);         \
    bf16x8 a10 = rdA(bufc, wm * 128 + ((q) * 2 + 1) * 16 + l15, 0);         \
    bf16x8 a11 = rdA(bufc, wm * 128 + ((q) * 2 + 1) * 16 + l15, 1);         \
    STG;                                                                    \
    if (LB && BN == 256) asm volatile("s_waitcnt lgkmcnt(8)" ::: "memory"); \
    __builtin_amdgcn_s_barrier();                                           \
    asm volatile("s_waitcnt lgkmcnt(0)" ::: "memory");                      \
    __builtin_amdgcn_sched_barrier(0);                                      \
    __builtin_amdgcn_s_setprio(1);                                          \
    _Pragma("unroll")                                                       \
    for (int n = 0; n < NFR; ++n) {                                         \
      acc[(q) * 2 + 0][n] = __builtin_amdgcn_mfma_f32_16x16x32_bf16(        \
          a00, Bf[n][0], acc[(q) * 2 + 0][n], 0, 0, 0);                     \
      acc[(q) * 2 + 0][n] = __builtin_amdgcn_mfma_f32_16x16x32_bf16(        \
          a01, Bf[n][1], acc[(q) * 2 + 0][n], 0, 0, 0);                     \
      acc[(q) * 2 + 1][n] = __builtin_amdgcn_mfma_f32_16x16x32_bf16(        \
          a10, Bf[n][0], acc[(q) * 2 + 1][n], 0, 0, 0);                     \
      acc[(q) * 2 + 1][n] = __builtin_amdgcn_mfma_f32_16x16x32_bf16(        \
          a11, Bf[n][1], acc[(q) * 2 + 1][n], 0, 0, 0);                     \
    }                                                                       \
    __builtin_amdgcn_s_setprio(0);                                          \
    EPI;                                                                    \
    {                                                                       \
      const int _vm = (VM);                                                 \
      if (_vm == 1) VMC_STEADY();                                           \
      else if (_vm == 2) asm volatile("s_waitcnt vmcnt(0)" ::: "memory");   \
    }                                                                       \
    __builtin_amdgcn_s_barrier();                                           \
    __builtin_amdgcn_sched_barrier(0);                                      \
  } while (0)

  const int nt = KK >> 6;        // K-tiles (even, >= 4)
  const int nit = nt >> 1;

  // prologue: buf0 <- tile0 (A+B), buf1.B <- tile1
  stA(0, 0, 0); stA(0, 1, 0); stB(0, 0, 0); stB(0, 1, 0);
  stB(1, 0, 1); stB(1, 1, 1);
  VMC_STEADY();
  __builtin_amdgcn_s_barrier();
  __builtin_amdgcn_sched_barrier(0);

#pragma unroll 1
  for (int it = 0; it < nit - 1; ++it) {
    const int t1 = 2 * it + 1, t2 = 2 * it + 2, t3 = 2 * it + 3;  // all < nt
    PHASE(0, 0, true,  { stA(1, 0, t1); }, 0, );            // ph1
    PHASE(0, 1, false, { stA(1, 1, t1); }, 0, );            // ph2
    PHASE(0, 2, false, { stB(0, 0, t2); }, 0, );            // ph3
    PHASE(0, 3, false, { stB(0, 1, t2); }, 1, );            // ph4
    PHASE(1, 0, true,  { stA(0, 0, t2); }, 0, );            // ph5
    PHASE(1, 1, false, { stA(0, 1, t2); }, 0, );            // ph6
    PHASE(1, 2, false, { stB(1, 0, t3); }, 0, );            // ph7
    PHASE(1, 3, false, { stB(1, 1, t3); }, 1, );            // ph8
  }
  {  // peeled final iteration: stores overlap ph5-8
    const int t1 = nt - 1;
    PHASE(0, 0, true,  { stA(1, 0, t1); }, 0, );
    PHASE(0, 1, false, { stA(1, 1, t1); }, 0, );
    PHASE(0, 2, false, { }, 0, );
    PHASE(0, 3, false, { }, 2, );                           // drain A1+B1
    PHASE(1, 0, true,  { }, 0, STOREQ(0));
    PHASE(1, 1, false, { }, 0, STOREQ(1));
    PHASE(1, 2, false, { }, 0, STOREQ(2));
    PHASE(1, 3, false, { }, 0, STOREQ(3));
  }
#undef PHASE
#undef STOREQ
#undef VMC_STEADY
}

extern "C" void kernel_launch(void* const* d_in, const int* in_sizes, int n_in,
                              void* d_out, int out_size, void* d_ws, size_t ws_size,
                              hipStream_t stream) {
  (void)in_sizes; (void)n_in; (void)out_size; (void)ws_size;
  const float* img = (const float*)d_in[0];   // [8192][1024] f32
  const float* W   = (const float*)d_in[1];   // [1024][2048] f32, cols unit-norm

  float* Rr = (float*)d_out;                   // r = alpha*G0, f32 [8192][2048]
  float* Pp = Rr + (size_t)NB * NK;            // pred = alpha*(G0 @ W^T), f32 [8192][1024]

  char* ws = (char*)d_ws;
  ushort_t* imgbf = (ushort_t*)(ws + 0);          // 16,777,216 B [8192][1024]
  ushort_t* Wt    = (ushort_t*)(ws + 16777216);   //  4,194,304 B [2048][1024]
  ushort_t* Wbf   = (ushort_t*)(ws + 20971520);   //  4,194,304 B [1024][2048]
  ushort_t* G0sbf = (ushort_t*)(ws + 25165824);   //    524,288 B [128][2048] sample
  ushort_t* G0bf  = (ushort_t*)(ws + 25690112);   // 33,554,432 B [8192][2048]
  Ctrl*     ctrl  = (Ctrl*)(ws + 59244544);

  // prep: img->bf16 (blocks 0-511), W->Wbf+Wt tiled transpose (512-1023), ctrl=0
  conv_all_k<<<1024, 256, 0, stream>>>(img, W, imgbf, Wbf, Wt, ctrl);

  // sample a: G0s = img[0:128] @ W -> G0sbf, a += ||G0s||^2   (16 blocks)
  gemm_bt<0><<<16, 256, 0, stream>>>(imgbf, Wt, NM, 16, NK, G0sbf, ctrl);
  // sample b: ||G0s @ W^T||^2 -> b; last block solves T, alpha (8 blocks)
  gemm_bt<1><<<8, 256, 0, stream>>>(G0sbf, Wbf, NK, 8, NM, nullptr, ctrl);

  // r = alpha*(img @ W), also capture G0 bf16.  32x8 = 256 blocks, BN=256.
  gemm8ph<0, 256><<<256, 512, 0, stream>>>(imgbf, Wt, NM, 8, NK, Rr, G0bf, ctrl);
  // pred = alpha*(G0 @ W^T).  32x8 = 256 blocks, BN=128 (full GPU).
  gemm8ph<1, 128><<<256, 512, 0, stream>>>(G0bf, Wbf, NK, 8, NM, Pp, nullptr, ctrl);
}

// Round 8
// 169.433 us; speedup vs baseline: 1.3724x; 1.0292x over previous
//
#include <hip/hip_runtime.h>

// ---- problem constants ----
#define NB 8192      // batch rows
#define NM 1024      // image dim
#define NK 2048      // dictionary size

typedef unsigned short ushort_t;
using bf16x8 = __attribute__((ext_vector_type(8))) short;
using f32x4  = __attribute__((ext_vector_type(4))) float;

struct Ctrl { double a; double b; int done; int T; float alpha; };

__device__ __forceinline__ ushort_t f2bf(float f) {
  union { float f; unsigned u; } v; v.f = f;
  unsigned r = (v.u + 0x7FFFu + ((v.u >> 16) & 1u)) >> 16;  // RNE
  return (ushort_t)r;
}

__device__ __forceinline__ void gload_lds16(const void* g, void* l) {
  __builtin_amdgcn_global_load_lds(
      (const __attribute__((address_space(1))) unsigned int*)g,
      (__attribute__((address_space(3))) unsigned int*)l, 16, 0, 0);
}

// ============ fused prep: img->bf16, W->Wbf + tiled-transpose Wt, ctrl=0 =====
__global__ __launch_bounds__(256)
void conv_all_k(const float* __restrict__ img, const float* __restrict__ W,
                ushort_t* __restrict__ imgbf, ushort_t* __restrict__ Wbf,
                ushort_t* __restrict__ Wt, Ctrl* __restrict__ ctrl)
{
  const int tid = threadIdx.x;
  const int b = blockIdx.x;
  if (b < 512) {
    if (b == 0 && tid == 0) { ctrl->a = 0.0; ctrl->b = 0.0; ctrl->done = 0; }
    const int base = b * 4096;
#pragma unroll
    for (int i = 0; i < 16; ++i) {
      const int idx = base + i * 256 + tid;
      const float4 v = ((const float4*)img)[idx];
      ushort4 o;
      o.x = f2bf(v.x); o.y = f2bf(v.y); o.z = f2bf(v.z); o.w = f2bf(v.w);
      ((ushort4*)imgbf)[idx] = o;
    }
  } else {
    __shared__ ushort_t tile[64][65];
    const int bW = b - 512;                       // 512 tiles: 16(m) x 32(k)
    const int m0 = (bW >> 5) * 64, k0 = (bW & 31) * 64;
    const int r = tid >> 2, q = tid & 3;
    ushort_t loc[16];
#pragma unroll
    for (int j = 0; j < 4; ++j) {
      const float4 v = *(const float4*)&W[(size_t)(m0 + r) * NK + k0 + q * 16 + j * 4];
      loc[j * 4 + 0] = f2bf(v.x); loc[j * 4 + 1] = f2bf(v.y);
      loc[j * 4 + 2] = f2bf(v.z); loc[j * 4 + 3] = f2bf(v.w);
    }
#pragma unroll
    for (int j = 0; j < 4; ++j) {
      ushort4 o;
      o.x = loc[j * 4 + 0]; o.y = loc[j * 4 + 1];
      o.z = loc[j * 4 + 2]; o.w = loc[j * 4 + 3];
      *(ushort4*)&Wbf[(size_t)(m0 + r) * NK + k0 + q * 16 + j * 4] = o;
    }
#pragma unroll
    for (int jj = 0; jj < 16; ++jj) tile[r][q * 16 + jj] = loc[jj];
    __syncthreads();
    const int kk = tid >> 2, qq = tid & 3;
#pragma unroll
    for (int j = 0; j < 4; ++j) {
      ushort4 o;
      o.x = tile[qq * 16 + j * 4 + 0][kk];
      o.y = tile[qq * 16 + j * 4 + 1][kk];
      o.z = tile[qq * 16 + j * 4 + 2][kk];
      o.w = tile[qq * 16 + j * 4 + 3][kk];
      *(ushort4*)&Wt[(size_t)(k0 + kk) * NM + m0 + qq * 16 + j * 4] = o;
    }
  }
}

// ================= shared 128^2 m97-style GEMM body (dynamic LDS) ============
// C = Aop * Bop^T. WBF: write bf16 C. NORM: -1 none, 0 -> ctrl->a, 1 -> ctrl->b.
// SOLVE: last-finisher ticket (nticket blocks) runs the T/alpha recurrence.
template<bool WBF, int NORM, bool SOLVE>
__device__ __forceinline__ void gemm128_body(
    const ushort_t* __restrict__ Aop, const ushort_t* __restrict__ Bop,
    int KK, int njb, int outld,
    ushort_t* __restrict__ outbf, Ctrl* __restrict__ ctrl, int bid, int nticket)
{
  extern __shared__ char smem_raw[];
  ushort_t* As = (ushort_t*)smem_raw;                 // 128*64 = 16384 B
  ushort_t* Bs = (ushort_t*)(smem_raw + 16384);       // 16384 B
  double*  red = (double*)(smem_raw + 32768);         // 32 B

  const int tid = threadIdx.x;
  const int w = tid >> 6, l = tid & 63;
  const int wm = w >> 1, wn = w & 1;
  const int bi = bid / njb, bj = bid % njb;
  const int i0 = bi * 128, j0 = bj * 128;
  const int l15 = l & 15, l16 = l >> 4;
  const int lr = l >> 3;
  const int lc = (l & 7) * 8;

  f32x4 acc[4][4];
#pragma unroll
  for (int m = 0; m < 4; ++m)
#pragma unroll
    for (int n = 0; n < 4; ++n)
      acc[m][n] = (f32x4){0.f, 0.f, 0.f, 0.f};

  for (int k0 = 0; k0 < KK; k0 += 64) {
#pragma unroll
    for (int c = 0; c < 4; ++c) {
      const int rr = c * 32 + w * 8 + lr;
      const ushort_t* ga = Aop + ((size_t)(i0 + rr) * (size_t)KK + k0 + lc);
      const ushort_t* gb = Bop + ((size_t)(j0 + rr) * (size_t)KK + k0 + lc);
      const int base = w * 512 + c * 2048;
      gload_lds16(ga, &As[base]);
      gload_lds16(gb, &Bs[base]);
    }
    __syncthreads();
#pragma unroll
    for (int ks = 0; ks < 2; ++ks) {
      bf16x8 af[4], bfr[4];
#pragma unroll
      for (int m = 0; m < 4; ++m)
        af[m] = *(const bf16x8*)&As[(wm * 64 + m * 16 + l15) * 64 + ks * 32 + l16 * 8];
#pragma unroll
      for (int n = 0; n < 4; ++n)
        bfr[n] = *(const bf16x8*)&Bs[(wn * 64 + n * 16 + l15) * 64 + ks * 32 + l16 * 8];
#pragma unroll
      for (int m = 0; m < 4; ++m)
#pragma unroll
        for (int n = 0; n < 4; ++n)
          acc[m][n] = __builtin_amdgcn_mfma_f32_16x16x32_bf16(af[m], bfr[n], acc[m][n], 0, 0, 0);
    }
    __syncthreads();
  }

  double sq = 0.0;
#pragma unroll
  for (int m = 0; m < 4; ++m)
#pragma unroll
    for (int n = 0; n < 4; ++n) {
      const int gr0 = i0 + wm * 64 + m * 16 + l16 * 4;
      const int gc  = j0 + wn * 64 + n * 16 + l15;
#pragma unroll
      for (int q = 0; q < 4; ++q) {
        const float v = acc[m][n][q];
        if constexpr (WBF)
          outbf[(size_t)(gr0 + q) * (size_t)outld + gc] = f2bf(v);
        if constexpr (NORM >= 0) sq += (double)v * (double)v;
      }
    }
  if constexpr (NORM >= 0) {
#pragma unroll
    for (int off = 32; off > 0; off >>= 1) sq += __shfl_down(sq, off, 64);
    if (l == 0) red[w] = sq;
    __syncthreads();
    if (tid == 0) {
      const double tot = red[0] + red[1] + red[2] + red[3];
      if constexpr (NORM == 0) atomicAdd(&ctrl->a, tot);
      else                     atomicAdd(&ctrl->b, tot);
      if constexpr (SOLVE) {
        __threadfence();
        if (atomicAdd(&ctrl->done, 1) == nticket - 1) {
          __threadfence();
          const double a = atomicAdd(&ctrl->a, 0.0);
          const double b = atomicAdd(&ctrl->b, 0.0);
          // Krylov-basis recurrence: r_t = t*s*G0 - s^2 t(t-1)/2 * G0A;
          // homogeneous in (a,b) -> sampled norms valid.
          const double s = 0.1 * (2.0 / 8388608.0);
          int T = 10000;
          for (int t = 1; t <= 10000; ++t) {
            const double ap = (double)(t - 1) * s;
            const double bp = -s * s * (double)(t - 1) * (double)(t - 2) * 0.5;
            const double num = s * s * (a - 2.0 * ap * b);
            const double den = ap * ap * a + 2.0 * ap * bp * b;
            if (den > 0.0 && num < 1e-4 * den) { T = t; break; }
          }
          ctrl->T = T;
          ctrl->alpha = (float)((double)T * s);
        }
      }
    }
  }
}

// fused: blocks 0-15: a-sample G0s = img[0:128]@W -> G0sbf + ||.||^2 -> a
//        blocks 16-79: Q = W@W^T -> Qbf  (1024x1024, KK=2048)
__global__ __launch_bounds__(256)
void spaq_k(const ushort_t* __restrict__ imgbf, const ushort_t* __restrict__ Wt,
            const ushort_t* __restrict__ Wbf, ushort_t* __restrict__ G0sbf,
            ushort_t* __restrict__ Qbf, Ctrl* __restrict__ ctrl)
{
  if (blockIdx.x < 16)
    gemm128_body<true, 0, false>(imgbf, Wt, NM, 16, NK, G0sbf, ctrl, blockIdx.x, 0);
  else
    gemm128_body<true, -1, false>(Wbf, Wbf, NK, 8, NM, Qbf, ctrl, blockIdx.x - 16, 0);
}

// b-sample: ||G0s @ W^T||^2 -> b; last of 8 blocks solves T, alpha
__global__ __launch_bounds__(256)
void spb_k(const ushort_t* __restrict__ G0sbf, const ushort_t* __restrict__ Wbf,
           Ctrl* __restrict__ ctrl)
{
  gemm128_body<false, 1, true>(G0sbf, Wbf, NK, 8, 1, nullptr, ctrl, blockIdx.x, 8);
}

// ============== 256xBN 8-phase deep-pipelined GEMM (finals) ==================
// C = Aop * Bop^T, tile 256xBN, BK=64, 512 threads (8 waves, 2Mx4N).
// Steady iter (2 K-tiles): 8 phases {ds_read subtile | stage 1 half-tile |
// barrier | lgkmcnt(0) | setprio+16 MFMA | [vmcnt] | barrier}; counted vmcnt
// at ph4/ph8 only. Last iteration peeled: quadrant stores overlap ph5-8.
// XOR swizzle byte^=(row&7)<<4 : inverse-swizzled global src, swizzled ds_read.
// outf = alpha*C (f32).
template<int BN>
__global__ __launch_bounds__(512, 2)
void gemm8ph(const ushort_t* __restrict__ Aop, const ushort_t* __restrict__ Bop,
             int KK, int njb, int outld,
             float* __restrict__ outf, const Ctrl* __restrict__ ctrl)
{
  constexpr int WN  = BN / 4;    // wave N extent (64 or 32)
  constexpr int NFR = BN / 64;   // B frags per wave (4 or 2)

  const int tid = threadIdx.x;
  const int w = tid >> 6, l = tid & 63;
  const int wm = w >> 2, wn = w & 3;
  // XCD-aware swizzle (grid % 8 == 0)
  const int wg = (blockIdx.x & 7) * ((int)gridDim.x >> 3) + ((int)blockIdx.x >> 3);
  const int bi = wg / njb, bj = wg % njb;
  const int i0 = bi * 256, j0 = bj * BN;
  const int l15 = l & 15, l16 = l >> 4;
  const int srow8 = l >> 3;          // lane row-in-8 for staging
  const int scb   = (l & 7) << 4;    // lane byte col for staging

  const float al = ctrl->alpha;      // ready before launch (solve done)

  __shared__ __align__(1024) ushort_t ldsA[2][256 * 64];
  __shared__ __align__(1024) ushort_t ldsB[2][BN * 64];

  f32x4 acc[8][NFR];
#pragma unroll
  for (int m = 0; m < 8; ++m)
#pragma unroll
    for (int n = 0; n < NFR; ++n)
      acc[m][n] = (f32x4){0.f, 0.f, 0.f, 0.f};
  bf16x8 Bf[NFR][2];

  auto SH2 = [&](ushort_t* lb, const ushort_t* g0) {   // 128-row half
#pragma unroll
    for (int c = 0; c < 2; ++c) {
      const int row = (w * 2 + c) * 8 + srow8;
      const int sc = (scb ^ ((row & 7) << 4)) >> 1;
      gload_lds16(g0 + (size_t)row * (size_t)KK + sc, lb + (w * 2 + c) * 512);
    }
  };
  auto SH1 = [&](ushort_t* lb, const ushort_t* g0) {   // 64-row half
    const int row = w * 8 + srow8;
    const int sc = (scb ^ ((row & 7) << 4)) >> 1;
    gload_lds16(g0 + (size_t)row * (size_t)KK + sc, lb + w * 512);
  };
  auto stA = [&](int buf, int half, int kt) {
    SH2(&ldsA[buf][half * (128 * 64)],
        Aop + (size_t)(i0 + half * 128) * (size_t)KK + (size_t)kt * 64);
  };
  auto stB = [&](int buf, int half, int kt) {
    if constexpr (BN == 256)
      SH2(&ldsB[buf][half * (128 * 64)],
          Bop + (size_t)(j0 + half * 128) * (size_t)KK + (size_t)kt * 64);
    else
      SH1(&ldsB[buf][half * (64 * 64)],
          Bop + (size_t)(j0 + half * 64) * (size_t)KK + (size_t)kt * 64);
  };
  auto rdA = [&](int buf, int R, int ks) -> bf16x8 {
    const int bc = ((ks * 64 + l16 * 16) ^ ((R & 7) << 4)) >> 1;
    return *(const bf16x8*)&ldsA[buf][R * 64 + bc];
  };
  auto rdB = [&](int buf, int R, int ks) -> bf16x8 {
    const int bc = ((ks * 64 + l16 * 16) ^ ((R & 7) << 4)) >> 1;
    return *(const bf16x8*)&ldsB[buf][R * 64 + bc];
  };

#define VMC_STEADY() do { \
    if constexpr (BN == 256) asm volatile("s_waitcnt vmcnt(4)" ::: "memory"); \
    else                     asm volatile("s_waitcnt vmcnt(2)" ::: "memory"); } while (0)

// store one C-quadrant (overlapped into peeled phases)
#define STOREQ(qd)                                                          \
  do {                                                                      \
    _Pragma("unroll")                                                       \
    for (int mm = 0; mm < 2; ++mm) {                                        \
      const int m = (qd) * 2 + mm;                                          \
      const int gr0 = i0 + wm * 128 + m * 16 + l16 * 4;                     \
      _Pragma("unroll")                                                     \
      for (int n = 0; n < NFR; ++n) {                                       \
        const int gc = j0 + wn * WN + n * 16 + l15;                         \
        _Pragma("unroll")                                                   \
        for (int qq = 0; qq < 4; ++qq) {                                    \
          const size_t idx = (size_t)(gr0 + qq) * (size_t)outld + gc;       \
          outf[idx] = al * acc[m][n][qq];                                   \
        }                                                                   \
      }                                                                     \
    }                                                                       \
  } while (0)

  // PHASE: LB=load Bf from bufc; STG=stage stmt; VM: 0 none 1 steady 2 drain;
  // EPI = post-MFMA statement (stores)
#define PHASE(bufc, q, LB, STG, VM, EPI)                                    \
  do {                                                                      \
    if (LB) {                                                               \
      _Pragma("unroll")                                                     \
      for (int n = 0; n < NFR; ++n) {                                       \
        Bf[n][0] = rdB(bufc, wn * WN + n * 16 + l15, 0);                    \
        Bf[n][1] = rdB(bufc, wn * WN + n * 16 + l15, 1);                    \
      }                                                                     \
    }                                                                       \
    bf16x8 a00 = rdA(bufc, wm * 128 + ((q) * 2 + 0) * 16 + l15, 0);         \
    bf16x8 a01 = rdA(bufc, wm * 128 + ((q) * 2 + 0) * 16 + l15, 1);         \
    bf16x8 a10 = rdA(bufc, wm * 128 + ((q) * 2 + 1) * 16 + l15, 0);         \
    bf16x8 a11 = rdA(bufc, wm * 128 + ((q) * 2 + 1) * 16 + l15, 1);         \
    STG;                                                                    \
    if (LB && BN == 256) asm volatile("s_waitcnt lgkmcnt(8)" ::: "memory"); \
    __builtin_amdgcn_s_barrier();                                           \
    asm volatile("s_waitcnt lgkmcnt(0)" ::: "memory");                      \
    __builtin_amdgcn_sched_barrier(0);                                      \
    __builtin_amdgcn_s_setprio(1);                                          \
    _Pragma("unroll")                                                       \
    for (int n = 0; n < NFR; ++n) {                                         \
      acc[(q) * 2 + 0][n] = __builtin_amdgcn_mfma_f32_16x16x32_bf16(        \
          a00, Bf[n][0], acc[(q) * 2 + 0][n], 0, 0, 0);                     \
      acc[(q) * 2 + 0][n] = __builtin_amdgcn_mfma_f32_16x16x32_bf16(        \
          a01, Bf[n][1], acc[(q) * 2 + 0][n], 0, 0, 0);                     \
      acc[(q) * 2 + 1][n] = __builtin_amdgcn_mfma_f32_16x16x32_bf16(        \
          a10, Bf[n][0], acc[(q) * 2 + 1][n], 0, 0, 0);                     \
      acc[(q) * 2 + 1][n] = __builtin_amdgcn_mfma_f32_16x16x32_bf16(        \
          a11, Bf[n][1], acc[(q) * 2 + 1][n], 0, 0, 0);                     \
    }                                                                       \
    __builtin_amdgcn_s_setprio(0);                                          \
    EPI;                                                                    \
    {                                                                       \
      const int _vm = (VM);                                                 \
      if (_vm == 1) VMC_STEADY();                                           \
      else if (_vm == 2) asm volatile("s_waitcnt vmcnt(0)" ::: "memory");   \
    }                                                                       \
    __builtin_amdgcn_s_barrier();                                           \
    __builtin_amdgcn_sched_barrier(0);                                      \
  } while (0)

  const int nt = KK >> 6;        // K-tiles (even, >= 4)
  const int nit = nt >> 1;

  // prologue: buf0 <- tile0 (A+B), buf1.B <- tile1
  stA(0, 0, 0); stA(0, 1, 0); stB(0, 0, 0); stB(0, 1, 0);
  stB(1, 0, 1); stB(1, 1, 1);
  VMC_STEADY();
  __builtin_amdgcn_s_barrier();
  __builtin_amdgcn_sched_barrier(0);

#pragma unroll 1
  for (int it = 0; it < nit - 1; ++it) {
    const int t1 = 2 * it + 1, t2 = 2 * it + 2, t3 = 2 * it + 3;  // all < nt
    PHASE(0, 0, true,  { stA(1, 0, t1); }, 0, );            // ph1
    PHASE(0, 1, false, { stA(1, 1, t1); }, 0, );            // ph2
    PHASE(0, 2, false, { stB(0, 0, t2); }, 0, );            // ph3
    PHASE(0, 3, false, { stB(0, 1, t2); }, 1, );            // ph4
    PHASE(1, 0, true,  { stA(0, 0, t2); }, 0, );            // ph5
    PHASE(1, 1, false, { stA(0, 1, t2); }, 0, );            // ph6
    PHASE(1, 2, false, { stB(1, 0, t3); }, 0, );            // ph7
    PHASE(1, 3, false, { stB(1, 1, t3); }, 1, );            // ph8
  }
  {  // peeled final iteration: stores overlap ph5-8
    const int t1 = nt - 1;
    PHASE(0, 0, true,  { stA(1, 0, t1); }, 0, );
    PHASE(0, 1, false, { stA(1, 1, t1); }, 0, );
    PHASE(0, 2, false, { }, 0, );
    PHASE(0, 3, false, { }, 2, );                           // drain A1+B1
    PHASE(1, 0, true,  { }, 0, STOREQ(0));
    PHASE(1, 1, false, { }, 0, STOREQ(1));
    PHASE(1, 2, false, { }, 0, STOREQ(2));
    PHASE(1, 3, false, { }, 0, STOREQ(3));
  }
#undef PHASE
#undef STOREQ
#undef VMC_STEADY
}

extern "C" void kernel_launch(void* const* d_in, const int* in_sizes, int n_in,
                              void* d_out, int out_size, void* d_ws, size_t ws_size,
                              hipStream_t stream) {
  (void)in_sizes; (void)n_in; (void)out_size; (void)ws_size;
  const float* img = (const float*)d_in[0];   // [8192][1024] f32
  const float* W   = (const float*)d_in[1];   // [1024][2048] f32, cols unit-norm

  float* Rr = (float*)d_out;                   // r = alpha*(img@W), f32 [8192][2048]
  float* Pp = Rr + (size_t)NB * NK;            // pred = alpha*(img@Q), f32 [8192][1024]

  char* ws = (char*)d_ws;
  ushort_t* imgbf = (ushort_t*)(ws + 0);          // 16,777,216 B [8192][1024]
  ushort_t* Wt    = (ushort_t*)(ws + 16777216);   //  4,194,304 B [2048][1024]
  ushort_t* Wbf   = (ushort_t*)(ws + 20971520);   //  4,194,304 B [1024][2048]
  ushort_t* G0sbf = (ushort_t*)(ws + 25165824);   //    524,288 B [128][2048] sample
  ushort_t* Qbf   = (ushort_t*)(ws + 25690112);   //  2,097,152 B [1024][1024]
  Ctrl*     ctrl  = (Ctrl*)(ws + 27787264);

  // prep: img->bf16 (blocks 0-511), W->Wbf+Wt tiled transpose (512-1023), ctrl=0
  conv_all_k<<<1024, 256, 0, stream>>>(img, W, imgbf, Wbf, Wt, ctrl);

  // fused: a-sample (16 blocks) + Q = W@W^T (64 blocks); 32,800 B dynamic LDS
  spaq_k<<<80, 256, 32800, stream>>>(imgbf, Wt, Wbf, G0sbf, Qbf, ctrl);

  // b-sample: ||G0s @ W^T||^2 -> b; last block solves T, alpha (8 blocks)
  spb_k<<<8, 256, 32800, stream>>>(G0sbf, Wbf, ctrl);

  // r = alpha*(img @ W).  32x8 = 256 blocks, BN=256, K=1024.
  gemm8ph<256><<<256, 512, 0, stream>>>(imgbf, Wt, NM, 8, NK, Rr, ctrl);
  // pred = alpha*(img @ Q) (Q symmetric). 32x8 = 256 blocks, BN=128, K=1024.
  gemm8ph<128><<<256, 512, 0, stream>>>(imgbf, Qbf, NM, 8, NM, Pp, ctrl);
}

// Round 9
// 102.295 us; speedup vs baseline: 2.2732x; 1.6563x over previous
//
#include <hip/hip_runtime.h>

// ---- problem constants ----
#define NB 8192      // batch rows
#define NM 1024      // image dim
#define NK 2048      // dictionary size

typedef unsigned short ushort_t;
using bf16x8 = __attribute__((ext_vector_type(8))) short;
using f32x4  = __attribute__((ext_vector_type(4))) float;

// T = 101 provably (see analysis): accept at t=101 holds for all b/a > 0;
// flip at t=100 would need b/a >= ~4e6 but b/a <= tr(W W^T) = 2048.
// Reproduce solve_k's exact double arithmetic, then cast.
__device__ __forceinline__ float alpha_const() {
  const double s = 0.1 * (2.0 / 8388608.0);
  return (float)(101.0 * s);
}

__device__ __forceinline__ ushort_t f2bf(float f) {
  union { float f; unsigned u; } v; v.f = f;
  unsigned r = (v.u + 0x7FFFu + ((v.u >> 16) & 1u)) >> 16;  // RNE
  return (ushort_t)r;
}

__device__ __forceinline__ void gload_lds16(const void* g, void* l) {
  __builtin_amdgcn_global_load_lds(
      (const __attribute__((address_space(1))) unsigned int*)g,
      (__attribute__((address_space(3))) unsigned int*)l, 16, 0, 0);
}

// ============ fused prep: img->bf16, W->Wbf + tiled-transpose Wt =============
__global__ __launch_bounds__(256)
void conv_all_k(const float* __restrict__ img, const float* __restrict__ W,
                ushort_t* __restrict__ imgbf, ushort_t* __restrict__ Wbf,
                ushort_t* __restrict__ Wt)
{
  const int tid = threadIdx.x;
  const int b = blockIdx.x;
  if (b < 512) {
    const int base = b * 4096;
#pragma unroll
    for (int i = 0; i < 16; ++i) {
      const int idx = base + i * 256 + tid;
      const float4 v = ((const float4*)img)[idx];
      ushort4 o;
      o.x = f2bf(v.x); o.y = f2bf(v.y); o.z = f2bf(v.z); o.w = f2bf(v.w);
      ((ushort4*)imgbf)[idx] = o;
    }
  } else {
    __shared__ ushort_t tile[64][65];
    const int bW = b - 512;                       // 512 tiles: 16(m) x 32(k)
    const int m0 = (bW >> 5) * 64, k0 = (bW & 31) * 64;
    const int r = tid >> 2, q = tid & 3;
    ushort_t loc[16];
#pragma unroll
    for (int j = 0; j < 4; ++j) {
      const float4 v = *(const float4*)&W[(size_t)(m0 + r) * NK + k0 + q * 16 + j * 4];
      loc[j * 4 + 0] = f2bf(v.x); loc[j * 4 + 1] = f2bf(v.y);
      loc[j * 4 + 2] = f2bf(v.z); loc[j * 4 + 3] = f2bf(v.w);
    }
#pragma unroll
    for (int j = 0; j < 4; ++j) {
      ushort4 o;
      o.x = loc[j * 4 + 0]; o.y = loc[j * 4 + 1];
      o.z = loc[j * 4 + 2]; o.w = loc[j * 4 + 3];
      *(ushort4*)&Wbf[(size_t)(m0 + r) * NK + k0 + q * 16 + j * 4] = o;
    }
#pragma unroll
    for (int jj = 0; jj < 16; ++jj) tile[r][q * 16 + jj] = loc[jj];
    __syncthreads();
    const int kk = tid >> 2, qq = tid & 3;
#pragma unroll
    for (int j = 0; j < 4; ++j) {
      ushort4 o;
      o.x = tile[qq * 16 + j * 4 + 0][kk];
      o.y = tile[qq * 16 + j * 4 + 1][kk];
      o.z = tile[qq * 16 + j * 4 + 2][kk];
      o.w = tile[qq * 16 + j * 4 + 3][kk];
      *(ushort4*)&Wt[(size_t)(k0 + kk) * NM + m0 + qq * 16 + j * 4] = o;
    }
  }
}

// ============ Q = bf16(W @ W^T), 64x64 tiles, 256 blocks (full GPU) ==========
// m97-style staging (gload_lds 16B), 4 waves as 2x2 of 32x32, K-step 64.
// Same per-element K-accumulation order as the 128^2 body -> bitwise-stable Q.
__global__ __launch_bounds__(256)
void qk64(const ushort_t* __restrict__ Wbf, ushort_t* __restrict__ Qbf)
{
  const int tid = threadIdx.x;
  const int w = tid >> 6, l = tid & 63;
  const int wm2 = w >> 1, wn2 = w & 1;
  const int bi = blockIdx.x >> 4, bj = blockIdx.x & 15;
  const int i0 = bi * 64, j0 = bj * 64;
  const int l15 = l & 15, l16 = l >> 4;
  const int lr = l >> 3;
  const int lc = (l & 7) * 8;

  __shared__ __align__(128) ushort_t As[64 * 64];
  __shared__ __align__(128) ushort_t Bs[64 * 64];

  f32x4 acc[2][2];
#pragma unroll
  for (int m = 0; m < 2; ++m)
#pragma unroll
    for (int n = 0; n < 2; ++n)
      acc[m][n] = (f32x4){0.f, 0.f, 0.f, 0.f};

  for (int k0 = 0; k0 < NK; k0 += 64) {
#pragma unroll
    for (int c = 0; c < 2; ++c) {
      const int rr = c * 32 + w * 8 + lr;
      const int base = c * 2048 + w * 512;
      gload_lds16(Wbf + (size_t)(i0 + rr) * NK + k0 + lc, &As[base]);
      gload_lds16(Wbf + (size_t)(j0 + rr) * NK + k0 + lc, &Bs[base]);
    }
    __syncthreads();
#pragma unroll
    for (int ks = 0; ks < 2; ++ks) {
      bf16x8 af[2], bfr[2];
#pragma unroll
      for (int m = 0; m < 2; ++m)
        af[m] = *(const bf16x8*)&As[(wm2 * 32 + m * 16 + l15) * 64 + ks * 32 + l16 * 8];
#pragma unroll
      for (int n = 0; n < 2; ++n)
        bfr[n] = *(const bf16x8*)&Bs[(wn2 * 32 + n * 16 + l15) * 64 + ks * 32 + l16 * 8];
#pragma unroll
      for (int m = 0; m < 2; ++m)
#pragma unroll
        for (int n = 0; n < 2; ++n)
          acc[m][n] = __builtin_amdgcn_mfma_f32_16x16x32_bf16(af[m], bfr[n], acc[m][n], 0, 0, 0);
    }
    __syncthreads();
  }

  // C/D layout: col = lane&15, row = (lane>>4)*4 + q
#pragma unroll
  for (int m = 0; m < 2; ++m)
#pragma unroll
    for (int n = 0; n < 2; ++n) {
      const int gr0 = i0 + wm2 * 32 + m * 16 + l16 * 4;
      const int gc  = j0 + wn2 * 32 + n * 16 + l15;
#pragma unroll
      for (int q = 0; q < 4; ++q)
        Qbf[(size_t)(gr0 + q) * NM + gc] = f2bf(acc[m][n][q]);
    }
}

// ============== 256xBN 8-phase deep-pipelined GEMM (finals) ==================
// C = Aop * Bop^T, tile 256xBN, BK=64, 512 threads (8 waves, 2Mx4N).
// Steady iter (2 K-tiles): 8 phases {ds_read subtile | stage 1 half-tile |
// barrier | lgkmcnt(0) | setprio+16 MFMA | [vmcnt] | barrier}; counted vmcnt
// at ph4/ph8 only. Last iteration peeled: quadrant stores overlap ph5-8.
// XOR swizzle byte^=(row&7)<<4 : inverse-swizzled global src, swizzled ds_read.
// outf = alpha*C (f32), alpha compile-time.
template<int BN>
__global__ __launch_bounds__(512, 2)
void gemm8ph(const ushort_t* __restrict__ Aop, const ushort_t* __restrict__ Bop,
             int KK, int njb, int outld, float* __restrict__ outf)
{
  constexpr int WN  = BN / 4;    // wave N extent (64 or 32)
  constexpr int NFR = BN / 64;   // B frags per wave (4 or 2)

  const int tid = threadIdx.x;
  const int w = tid >> 6, l = tid & 63;
  const int wm = w >> 2, wn = w & 3;
  // XCD-aware swizzle (grid % 8 == 0)
  const int wg = (blockIdx.x & 7) * ((int)gridDim.x >> 3) + ((int)blockIdx.x >> 3);
  const int bi = wg / njb, bj = wg % njb;
  const int i0 = bi * 256, j0 = bj * BN;
  const int l15 = l & 15, l16 = l >> 4;
  const int srow8 = l >> 3;          // lane row-in-8 for staging
  const int scb   = (l & 7) << 4;    // lane byte col for staging

  const float al = alpha_const();

  __shared__ __align__(1024) ushort_t ldsA[2][256 * 64];
  __shared__ __align__(1024) ushort_t ldsB[2][BN * 64];

  f32x4 acc[8][NFR];
#pragma unroll
  for (int m = 0; m < 8; ++m)
#pragma unroll
    for (int n = 0; n < NFR; ++n)
      acc[m][n] = (f32x4){0.f, 0.f, 0.f, 0.f};
  bf16x8 Bf[NFR][2];

  auto SH2 = [&](ushort_t* lb, const ushort_t* g0) {   // 128-row half
#pragma unroll
    for (int c = 0; c < 2; ++c) {
      const int row = (w * 2 + c) * 8 + srow8;
      const int sc = (scb ^ ((row & 7) << 4)) >> 1;
      gload_lds16(g0 + (size_t)row * (size_t)KK + sc, lb + (w * 2 + c) * 512);
    }
  };
  auto SH1 = [&](ushort_t* lb, const ushort_t* g0) {   // 64-row half
    const int row = w * 8 + srow8;
    const int sc = (scb ^ ((row & 7) << 4)) >> 1;
    gload_lds16(g0 + (size_t)row * (size_t)KK + sc, lb + w * 512);
  };
  auto stA = [&](int buf, int half, int kt) {
    SH2(&ldsA[buf][half * (128 * 64)],
        Aop + (size_t)(i0 + half * 128) * (size_t)KK + (size_t)kt * 64);
  };
  auto stB = [&](int buf, int half, int kt) {
    if constexpr (BN == 256)
      SH2(&ldsB[buf][half * (128 * 64)],
          Bop + (size_t)(j0 + half * 128) * (size_t)KK + (size_t)kt * 64);
    else
      SH1(&ldsB[buf][half * (64 * 64)],
          Bop + (size_t)(j0 + half * 64) * (size_t)KK + (size_t)kt * 64);
  };
  auto rdA = [&](int buf, int R, int ks) -> bf16x8 {
    const int bc = ((ks * 64 + l16 * 16) ^ ((R & 7) << 4)) >> 1;
    return *(const bf16x8*)&ldsA[buf][R * 64 + bc];
  };
  auto rdB = [&](int buf, int R, int ks) -> bf16x8 {
    const int bc = ((ks * 64 + l16 * 16) ^ ((R & 7) << 4)) >> 1;
    return *(const bf16x8*)&ldsB[buf][R * 64 + bc];
  };

#define VMC_STEADY() do { \
    if constexpr (BN == 256) asm volatile("s_waitcnt vmcnt(4)" ::: "memory"); \
    else                     asm volatile("s_waitcnt vmcnt(2)" ::: "memory"); } while (0)

// store one C-quadrant (overlapped into peeled phases)
#define STOREQ(qd)                                                          \
  do {                                                                      \
    _Pragma("unroll")                                                       \
    for (int mm = 0; mm < 2; ++mm) {                                        \
      const int m = (qd) * 2 + mm;                                          \
      const int gr0 = i0 + wm * 128 + m * 16 + l16 * 4;                     \
      _Pragma("unroll")                                                     \
      for (int n = 0; n < NFR; ++n) {                                       \
        const int gc = j0 + wn * WN + n * 16 + l15;                         \
        _Pragma("unroll")                                                   \
        for (int qq = 0; qq < 4; ++qq) {                                    \
          const size_t idx = (size_t)(gr0 + qq) * (size_t)outld + gc;       \
          outf[idx] = al * acc[m][n][qq];                                   \
        }                                                                   \
      }                                                                     \
    }                                                                       \
  } while (0)

  // PHASE: LB=load Bf from bufc; STG=stage stmt; VM: 0 none 1 steady 2 drain;
  // EPI = post-MFMA statement (stores)
#define PHASE(bufc, q, LB, STG, VM, EPI)                                    \
  do {                                                                      \
    if (LB) {                                                               \
      _Pragma("unroll")                                                     \
      for (int n = 0; n < NFR; ++n) {                                       \
        Bf[n][0] = rdB(bufc, wn * WN + n * 16 + l15, 0);                    \
        Bf[n][1] = rdB(bufc, wn * WN + n * 16 + l15, 1);                    \
      }                                                                     \
    }                                                                       \
    bf16x8 a00 = rdA(bufc, wm * 128 + ((q) * 2 + 0) * 16 + l15, 0);         \
    bf16x8 a01 = rdA(bufc, wm * 128 + ((q) * 2 + 0) * 16 + l15, 1);         \
    bf16x8 a10 = rdA(bufc, wm * 128 + ((q) * 2 + 1) * 16 + l15, 0);         \
    bf16x8 a11 = rdA(bufc, wm * 128 + ((q) * 2 + 1) * 16 + l15, 1);         \
    STG;                                                                    \
    if (LB && BN == 256) asm volatile("s_waitcnt lgkmcnt(8)" ::: "memory"); \
    __builtin_amdgcn_s_barrier();                                           \
    asm volatile("s_waitcnt lgkmcnt(0)" ::: "memory");                      \
    __builtin_amdgcn_sched_barrier(0);                                      \
    __builtin_amdgcn_s_setprio(1);                                          \
    _Pragma("unroll")                                                       \
    for (int n = 0; n < NFR; ++n) {                                         \
      acc[(q) * 2 + 0][n] = __builtin_amdgcn_mfma_f32_16x16x32_bf16(        \
          a00, Bf[n][0], acc[(q) * 2 + 0][n], 0, 0, 0);                     \
      acc[(q) * 2 + 0][n] = __builtin_amdgcn_mfma_f32_16x16x32_bf16(        \
          a01, Bf[n][1], acc[(q) * 2 + 0][n], 0, 0, 0);                     \
      acc[(q) * 2 + 1][n] = __builtin_amdgcn_mfma_f32_16x16x32_bf16(        \
          a10, Bf[n][0], acc[(q) * 2 + 1][n], 0, 0, 0);                     \
      acc[(q) * 2 + 1][n] = __builtin_amdgcn_mfma_f32_16x16x32_bf16(        \
          a11, Bf[n][1], acc[(q) * 2 + 1][n], 0, 0, 0);                     \
    }                                                                       \
    __builtin_amdgcn_s_setprio(0);                                          \
    EPI;                                                                    \
    {                                                                       \
      const int _vm = (VM);                                                 \
      if (_vm == 1) VMC_STEADY();                                           \
      else if (_vm == 2) asm volatile("s_waitcnt vmcnt(0)" ::: "memory");   \
    }                                                                       \
    __builtin_amdgcn_s_barrier();                                           \
    __builtin_amdgcn_sched_barrier(0);                                      \
  } while (0)

  const int nt = KK >> 6;        // K-tiles (even, >= 4)
  const int nit = nt >> 1;

  // prologue: buf0 <- tile0 (A+B), buf1.B <- tile1
  stA(0, 0, 0); stA(0, 1, 0); stB(0, 0, 0); stB(0, 1, 0);
  stB(1, 0, 1); stB(1, 1, 1);
  VMC_STEADY();
  __builtin_amdgcn_s_barrier();
  __builtin_amdgcn_sched_barrier(0);

#pragma unroll 1
  for (int it = 0; it < nit - 1; ++it) {
    const int t1 = 2 * it + 1, t2 = 2 * it + 2, t3 = 2 * it + 3;  // all < nt
    PHASE(0, 0, true,  { stA(1, 0, t1); }, 0, );            // ph1
    PHASE(0, 1, false, { stA(1, 1, t1); }, 0, );            // ph2
    PHASE(0, 2, false, { stB(0, 0, t2); }, 0, );            // ph3
    PHASE(0, 3, false, { stB(0, 1, t2); }, 1, );            // ph4
    PHASE(1, 0, true,  { stA(0, 0, t2); }, 0, );            // ph5
    PHASE(1, 1, false, { stA(0, 1, t2); }, 0, );            // ph6
    PHASE(1, 2, false, { stB(1, 0, t3); }, 0, );            // ph7
    PHASE(1, 3, false, { stB(1, 1, t3); }, 1, );            // ph8
  }
  {  // peeled final iteration: stores overlap ph5-8
    const int t1 = nt - 1;
    PHASE(0, 0, true,  { stA(1, 0, t1); }, 0, );
    PHASE(0, 1, false, { stA(1, 1, t1); }, 0, );
    PHASE(0, 2, false, { }, 0, );
    PHASE(0, 3, false, { }, 2, );                           // drain A1+B1
    PHASE(1, 0, true,  { }, 0, STOREQ(0));
    PHASE(1, 1, false, { }, 0, STOREQ(1));
    PHASE(1, 2, false, { }, 0, STOREQ(2));
    PHASE(1, 3, false, { }, 0, STOREQ(3));
  }
#undef PHASE
#undef STOREQ
#undef VMC_STEADY
}

extern "C" void kernel_launch(void* const* d_in, const int* in_sizes, int n_in,
                              void* d_out, int out_size, void* d_ws, size_t ws_size,
                              hipStream_t stream) {
  (void)in_sizes; (void)n_in; (void)out_size; (void)ws_size;
  const float* img = (const float*)d_in[0];   // [8192][1024] f32
  const float* W   = (const float*)d_in[1];   // [1024][2048] f32, cols unit-norm

  float* Rr = (float*)d_out;                   // r = alpha*(img@W), f32 [8192][2048]
  float* Pp = Rr + (size_t)NB * NK;            // pred = alpha*(img@Q), f32 [8192][1024]

  char* ws = (char*)d_ws;
  ushort_t* imgbf = (ushort_t*)(ws + 0);          // 16,777,216 B [8192][1024]
  ushort_t* Wt    = (ushort_t*)(ws + 16777216);   //  4,194,304 B [2048][1024]
  ushort_t* Wbf   = (ushort_t*)(ws + 20971520);   //  4,194,304 B [1024][2048]
  ushort_t* Qbf   = (ushort_t*)(ws + 25165824);   //  2,097,152 B [1024][1024]

  // prep: img->bf16 (blocks 0-511), W->Wbf+Wt tiled transpose (512-1023)
  conv_all_k<<<1024, 256, 0, stream>>>(img, W, imgbf, Wbf, Wt);

  // Q = bf16(W @ W^T): 16x16 = 256 blocks of 64x64 tiles, K=2048
  qk64<<<256, 256, 0, stream>>>(Wbf, Qbf);

  // r = alpha*(img @ W).  32x8 = 256 blocks, BN=256, K=1024.
  gemm8ph<256><<<256, 512, 0, stream>>>(imgbf, Wt, NM, 8, NK, Rr);
  // pred = alpha*(img @ Q) (Q symmetric). 32x8 = 256 blocks, BN=128, K=1024.
  gemm8ph<128><<<256, 512, 0, stream>>>(imgbf, Qbf, NM, 8, NM, Pp);
}